// Round 1
// baseline (1231.622 us; speedup 1.0000x reference)
//
#include <hip/hip_runtime.h>

#define L_SEQ 2048
#define CH    1024
#define NB    32
#define KSEL  20

typedef short v8s  __attribute__((ext_vector_type(8)));
typedef float v16f __attribute__((ext_vector_type(16)));

// ---------------- workspace layout (float offsets) ----------------
#define WS_XSUM   0          // [32*1024] f32   column sums of x
#define WS_YMAX   32768      // [32*1024] u32   encoded col-max of y
#define WS_M1     65536      // [32*1024] f32   mean-pool @ W^T + b
#define WS_AMAX   98304      // [32*1024] f32   decoded max-pool + b
#define WS_T1     131072     // [32*1024] f32
#define WS_T2     163840     // [32*1024] f32
#define WS_XM     196608     // [32*1024] f32
#define WS_XA     229376     // [32*1024] f32
#define WS_U      262144     // [32*1024] f32
#define WS_V      294912     // [32*1024] f32
#define WS_S      327680     // [32*2048] f32   logit sums
#define WS_TOPK   393216     // [640] int
#define WS_XSEL   393856     // [640*1024] f32
#define WS_YSEL   1049216    // [640*1024] f32

// ---------------- column means of x (atomic partial sums) ----------------
__global__ __launch_bounds__(256) void mean_kernel(const float* __restrict__ x,
                                                   float* __restrict__ xsum) {
  int b = blockIdx.y, chunk = blockIdx.x, t = threadIdx.x;
  const float4* bp = (const float4*)(x + ((size_t)b * L_SEQ + (size_t)chunk * 128) * CH);
  float sx = 0.f, sy = 0.f, sz = 0.f, sw = 0.f;
  #pragma unroll 4
  for (int l = 0; l < 128; ++l) {
    float4 a = bp[l * 256 + t];
    sx += a.x; sy += a.y; sz += a.z; sw += a.w;
  }
  float* dst = xsum + b * CH + t * 4;
  atomicAdd(dst + 0, sx); atomicAdd(dst + 1, sy);
  atomicAdd(dst + 2, sz); atomicAdd(dst + 3, sw);
}

// ---------------- fp32 -> (hi,lo) bf16 split, 8 elems -> two uint4 ----------------
__device__ __forceinline__ void split8(float4 qa, float4 qb, uint4& hi, uint4& lo) {
  float f[8] = {qa.x, qa.y, qa.z, qa.w, qb.x, qb.y, qb.z, qb.w};
  unsigned h[8], l[8];
  #pragma unroll
  for (int e = 0; e < 8; ++e) {
    unsigned u  = __float_as_uint(f[e]);
    unsigned hu = u & 0xFFFF0000u;                 // truncated hi bf16
    float lf    = f[e] - __uint_as_float(hu);      // residual
    h[e] = u >> 16;
    l[e] = __float_as_uint(lf) >> 16;              // truncated lo bf16
  }
  hi.x = h[0] | (h[1] << 16); hi.y = h[2] | (h[3] << 16);
  hi.z = h[4] | (h[5] << 16); hi.w = h[6] | (h[7] << 16);
  lo.x = l[0] | (l[1] << 16); lo.y = l[2] | (l[3] << 16);
  lo.z = l[4] | (l[5] << 16); lo.w = l[6] | (l[7] << 16);
}

// ---------------- big GEMM (split-bf16 x3) + column max ----------------
// C[m][n] = sum_k X[m][k] * W[n][k]; reduce max over m within batch -> ymax (encoded u32)
__global__ __launch_bounds__(256, 2) void gemm_max_kernel(const float* __restrict__ X,
                                                          const float* __restrict__ Wt,
                                                          unsigned* __restrict__ ymax) {
  __shared__ uint4 sm[2048];  // A frags [0,1024), B frags [1024,2048); frag-major layout
  const int t    = threadIdx.x;
  const int lane = t & 63, wv = t >> 6;
  const int wm   = wv >> 1, wn = wv & 1;
  const int n0   = blockIdx.x * 128;
  const int m0   = blockIdx.y * 128;
  const int batch = blockIdx.y >> 4;  // 128*16 = 2048 rows per batch

  const int r = t >> 1, half = t & 1, l0 = r & 31, mt = r >> 5;
  const float* Ap = X  + (size_t)(m0 + r) * CH + half * 16;
  const float* Bp = Wt + (size_t)(n0 + r) * CH + half * 16;

  v16f acc[2][2];
  #pragma unroll
  for (int i = 0; i < 2; ++i)
    #pragma unroll
    for (int j = 0; j < 2; ++j)
      #pragma unroll
      for (int e = 0; e < 16; ++e) acc[i][j][e] = 0.f;

  float4 apre[4], bpre[4];
  #pragma unroll
  for (int j = 0; j < 4; ++j) {
    apre[j] = *(const float4*)(Ap + j * 4);
    bpre[j] = *(const float4*)(Bp + j * 4);
  }

  const int segA = (mt * 2 + half) * 128;          // 64 hi slots + 64 lo slots
  const int segB = 1024 + (mt * 2 + half) * 128;

  for (int kt = 0; kt < 32; ++kt) {
    uint4 h0, h1, q0, q1;
    split8(apre[0], apre[1], h0, q0);
    split8(apre[2], apre[3], h1, q1);
    sm[segA + l0]      = h0; sm[segA + 32 + l0] = h1;
    sm[segA + 64 + l0] = q0; sm[segA + 96 + l0] = q1;
    split8(bpre[0], bpre[1], h0, q0);
    split8(bpre[2], bpre[3], h1, q1);
    sm[segB + l0]      = h0; sm[segB + 32 + l0] = h1;
    sm[segB + 64 + l0] = q0; sm[segB + 96 + l0] = q1;
    __syncthreads();

    if (kt < 31) {  // prefetch next K-slice (overlaps MFMA section)
      const float* An = Ap + (kt + 1) * 32;
      const float* Bn = Bp + (kt + 1) * 32;
      #pragma unroll
      for (int j = 0; j < 4; ++j) {
        apre[j] = *(const float4*)(An + j * 4);
        bpre[j] = *(const float4*)(Bn + j * 4);
      }
    }

    #pragma unroll
    for (int s = 0; s < 2; ++s) {
      v8s ah[2], al[2], bh[2], bl[2];
      #pragma unroll
      for (int i = 0; i < 2; ++i) {
        int base = ((wm * 2 + i) * 2 + s) * 128;
        ah[i] = *reinterpret_cast<const v8s*>(&sm[base + lane]);
        al[i] = *reinterpret_cast<const v8s*>(&sm[base + 64 + lane]);
      }
      #pragma unroll
      for (int j = 0; j < 2; ++j) {
        int base = 1024 + ((wn * 2 + j) * 2 + s) * 128;
        bh[j] = *reinterpret_cast<const v8s*>(&sm[base + lane]);
        bl[j] = *reinterpret_cast<const v8s*>(&sm[base + 64 + lane]);
      }
      #pragma unroll
      for (int i = 0; i < 2; ++i)
        #pragma unroll
        for (int j = 0; j < 2; ++j) {
          acc[i][j] = __builtin_amdgcn_mfma_f32_32x32x16_bf16(ah[i], bh[j], acc[i][j], 0, 0, 0);
          acc[i][j] = __builtin_amdgcn_mfma_f32_32x32x16_bf16(ah[i], bl[j], acc[i][j], 0, 0, 0);
          acc[i][j] = __builtin_amdgcn_mfma_f32_32x32x16_bf16(al[i], bh[j], acc[i][j], 0, 0, 0);
        }
    }
    __syncthreads();
  }

  // column-max epilogue: C/D layout col = lane&31 (rows spread over regs & lane>>5)
  #pragma unroll
  for (int j = 0; j < 2; ++j) {
    float m = -INFINITY;
    #pragma unroll
    for (int i = 0; i < 2; ++i)
      #pragma unroll
      for (int e = 0; e < 16; ++e) m = fmaxf(m, acc[i][j][e]);
    m = fmaxf(m, __shfl_xor(m, 32));
    if (lane < 32) {
      int col = n0 + wn * 64 + j * 32 + lane;
      unsigned u = __float_as_uint(m);
      unsigned enc = (m >= 0.f) ? (u | 0x80000000u) : ~u;  // order-preserving encode
      atomicMax(&ymax[batch * CH + col], enc);
    }
  }
}

// ---------------- decode encoded max + add linear bias ----------------
__global__ __launch_bounds__(256) void decode_kernel(const unsigned* __restrict__ ymax,
                                                     const float* __restrict__ bias,
                                                     float* __restrict__ amax) {
  int i = blockIdx.x * 256 + threadIdx.x;
  unsigned u = ymax[i];
  float f = (u & 0x80000000u) ? __uint_as_float(u & 0x7FFFFFFFu) : __uint_as_float(~u);
  amax[i] = f + bias[i & (CH - 1)];
}

// ---------------- O[b][d] = scale * sum_c I[b][c]*M[d][c] + bias[d] ----------------
__global__ __launch_bounds__(256) void rowdot_kernel(const float* __restrict__ I,
                                                     const float* __restrict__ M,
                                                     const float* __restrict__ bias,
                                                     float* __restrict__ O, float scale) {
  int t = threadIdx.x;
  int d = blockIdx.x * 8 + (t >> 5);
  int b = t & 31;
  const float4* Ir = (const float4*)(I + b * CH);
  const float4* Mr = (const float4*)(M + (size_t)d * CH);
  float acc = 0.f;
  #pragma unroll 4
  for (int c = 0; c < CH / 4; ++c) {
    float4 a = Ir[c], m = Mr[c];
    acc += a.x * m.x + a.y * m.y + a.z * m.z + a.w * m.w;
  }
  O[b * CH + d] = acc * scale + bias[d];
}

// ---------------- GroupNorm (32 groups of 32 channels), both branches ----------------
__global__ __launch_bounds__(1024) void gn_kernel(const float* __restrict__ t1, const float* __restrict__ t2,
                                                  const float* __restrict__ g1w, const float* __restrict__ g1b,
                                                  const float* __restrict__ g2w, const float* __restrict__ g2b,
                                                  float* __restrict__ xM, float* __restrict__ xA) {
  int which = blockIdx.x >> 5, b = blockIdx.x & 31, c = threadIdx.x;
  const float* in = which ? t2 : t1;
  const float* w  = which ? g2w : g1w;
  const float* bb = which ? g2b : g1b;
  float* out      = which ? xA : xM;
  float v = in[b * CH + c];
  float s = v;
  #pragma unroll
  for (int off = 16; off; off >>= 1) s += __shfl_xor(s, off);   // 32-ch groups align to half-waves
  float mean = s * (1.f / 32.f);
  float d = v - mean;
  float ss = d * d;
  #pragma unroll
  for (int off = 16; off; off >>= 1) ss += __shfl_xor(ss, off);
  out[b * CH + c] = d * rsqrtf(ss * (1.f / 32.f) + 1e-5f) * w[c] + bb[c];
}

// ---------------- O[b][e] += sum_{c in chunk} (S1+S2)[b][c] * M[c][e] ----------------
__global__ __launch_bounds__(256) void colmm_kernel(const float* __restrict__ S1,
                                                    const float* __restrict__ S2,
                                                    const float* __restrict__ M,
                                                    float* __restrict__ O) {
  __shared__ float Sl[128][32];
  int t = threadIdx.x;
  int e0 = (blockIdx.x & 3) * 256, c0 = (blockIdx.x >> 2) * 128;
  for (int i = t; i < 4096; i += 256) {
    int c = i >> 5, b = i & 31;
    float val = S1[b * CH + c0 + c];
    if (S2) val += S2[b * CH + c0 + c];
    Sl[c][b] = val;
  }
  __syncthreads();
  int e = e0 + t;
  float acc[32];
  #pragma unroll
  for (int b = 0; b < 32; ++b) acc[b] = 0.f;
  for (int c = 0; c < 128; ++c) {
    float wv = M[(size_t)(c0 + c) * CH + e];
    #pragma unroll
    for (int b = 0; b < 32; ++b) acc[b] += Sl[c][b] * wv;
  }
  #pragma unroll
  for (int b = 0; b < 32; ++b) atomicAdd(&O[b * CH + e], acc[b]);
}

// ---------------- logits s[b][l] = x[b][l][:] . v[b][:] ----------------
__global__ __launch_bounds__(256) void logits_kernel(const float* __restrict__ x,
                                                     const float* __restrict__ v,
                                                     float* __restrict__ s) {
  __shared__ float4 vl[256];
  int b = blockIdx.y, chunk = blockIdx.x, t = threadIdx.x;
  vl[t] = ((const float4*)(v + b * CH))[t];
  __syncthreads();
  int wv = t >> 6, lane = t & 63;
  for (int it = 0; it < 8; ++it) {
    int l = chunk * 32 + it * 4 + wv;
    const float4* xr = (const float4*)(x + ((size_t)b * L_SEQ + l) * CH);
    float acc = 0.f;
    #pragma unroll
    for (int rep = 0; rep < 4; ++rep) {
      float4 a = xr[rep * 64 + lane];
      float4 c = vl[rep * 64 + lane];
      acc += a.x * c.x + a.y * c.y + a.z * c.z + a.w * c.w;
    }
    #pragma unroll
    for (int off = 32; off; off >>= 1) acc += __shfl_xor(acc, off);
    if (lane == 0) s[b * L_SEQ + l] = acc;
  }
}

// ---------------- top-20 (desc, ties -> lower index) ----------------
__global__ __launch_bounds__(256) void topk_kernel(const float* __restrict__ s,
                                                   int* __restrict__ idx_out) {
  int b = blockIdx.x, t = threadIdx.x;
  __shared__ float sv[L_SEQ];
  __shared__ float rv[256];
  __shared__ int   ri[256];
  for (int i = t; i < L_SEQ; i += 256) sv[i] = s[b * L_SEQ + i];
  __syncthreads();
  for (int k = 0; k < KSEL; ++k) {
    float bv = -INFINITY; int bi = 1 << 30;
    for (int i = t; i < L_SEQ; i += 256) {
      float v = sv[i];
      if (v > bv || (v == bv && i < bi)) { bv = v; bi = i; }
    }
    rv[t] = bv; ri[t] = bi; __syncthreads();
    for (int off = 128; off > 0; off >>= 1) {
      if (t < off) {
        float v2 = rv[t + off]; int i2 = ri[t + off];
        if (v2 > rv[t] || (v2 == rv[t] && i2 < ri[t])) { rv[t] = v2; ri[t] = i2; }
      }
      __syncthreads();
    }
    if (t == 0) { idx_out[b * KSEL + k] = ri[0]; sv[ri[0]] = -INFINITY; }
    __syncthreads();
  }
}

// ---------------- gather selected x rows ----------------
__global__ __launch_bounds__(256) void gather_kernel(const float* __restrict__ x,
                                                     const int* __restrict__ idx,
                                                     float* __restrict__ Xsel) {
  int row = blockIdx.x;          // 0..639
  int b = row / KSEL;
  int l = idx[row];
  const float4* src = (const float4*)(x + ((size_t)b * L_SEQ + l) * CH);
  float4* dst = (float4*)(Xsel + (size_t)row * CH);
  dst[threadIdx.x] = src[threadIdx.x];
}

// ---------------- exact fp32 GEMM for selected rows: C = A * B^T + bias ----------------
__global__ __launch_bounds__(256) void selgemm_kernel(const float* __restrict__ A,
                                                      const float* __restrict__ B,
                                                      const float* __restrict__ bias,
                                                      float* __restrict__ C) {
  __shared__ float As[64][17];
  __shared__ float Bs[64][17];
  int t = threadIdx.x;
  int tx = t & 15, ty = t >> 4;
  int n0 = blockIdx.x * 64, m0 = blockIdx.y * 64;
  float acc[4][4];
  #pragma unroll
  for (int i = 0; i < 4; ++i)
    #pragma unroll
    for (int j = 0; j < 4; ++j) acc[i][j] = 0.f;
  for (int k0 = 0; k0 < CH; k0 += 16) {
    #pragma unroll
    for (int j = 0; j < 4; ++j) {
      int e = t * 4 + j;
      int row = e >> 4, kk = e & 15;
      As[row][kk] = A[(size_t)(m0 + row) * CH + k0 + kk];
      Bs[row][kk] = B[(size_t)(n0 + row) * CH + k0 + kk];
    }
    __syncthreads();
    #pragma unroll
    for (int kk = 0; kk < 16; ++kk) {
      float a[4], bb[4];
      #pragma unroll
      for (int i = 0; i < 4; ++i) a[i] = As[ty * 4 + i][kk];
      #pragma unroll
      for (int j = 0; j < 4; ++j) bb[j] = Bs[tx * 4 + j][kk];
      #pragma unroll
      for (int i = 0; i < 4; ++i)
        #pragma unroll
        for (int j = 0; j < 4; ++j) acc[i][j] += a[i] * bb[j];
    }
    __syncthreads();
  }
  #pragma unroll
  for (int i = 0; i < 4; ++i)
    #pragma unroll
    for (int j = 0; j < 4; ++j)
      C[(size_t)(m0 + ty * 4 + i) * CH + n0 + tx * 4 + j] = acc[i][j] + bias[n0 + tx * 4 + j];
}

extern "C" void kernel_launch(void* const* d_in, const int* in_sizes, int n_in,
                              void* d_out, int out_size, void* d_ws, size_t ws_size,
                              hipStream_t stream) {
  const float* x   = (const float*)d_in[0];
  const float* W   = (const float*)d_in[1];
  const float* b   = (const float*)d_in[2];
  const float* W1  = (const float*)d_in[3];
  const float* b1  = (const float*)d_in[4];
  const float* Wm  = (const float*)d_in[5];
  const float* bm  = (const float*)d_in[6];
  const float* Wa  = (const float*)d_in[7];
  const float* ba  = (const float*)d_in[8];
  const float* g1w = (const float*)d_in[9];
  const float* g1b = (const float*)d_in[10];
  const float* g2w = (const float*)d_in[11];
  const float* g2b = (const float*)d_in[12];

  float* wsf = (float*)d_ws;
  float*    xsum = wsf + WS_XSUM;
  unsigned* ymax = (unsigned*)(wsf + WS_YMAX);
  float*    m1   = wsf + WS_M1;
  float*    amax = wsf + WS_AMAX;
  float*    t1   = wsf + WS_T1;
  float*    t2   = wsf + WS_T2;
  float*    xM   = wsf + WS_XM;
  float*    xA   = wsf + WS_XA;
  float*    u    = wsf + WS_U;
  float*    vvec = wsf + WS_V;
  float*    sbuf = wsf + WS_S;
  int*      tidx = (int*)(wsf + WS_TOPK);
  float*    Xsel = wsf + WS_XSEL;
  float*    Ysel = wsf + WS_YSEL;

  // zero: xsum + ymax (contiguous), u + v (contiguous)
  hipMemsetAsync(wsf + WS_XSUM, 0, 65536 * sizeof(float), stream);
  hipMemsetAsync(wsf + WS_U,    0, 65536 * sizeof(float), stream);

  mean_kernel<<<dim3(16, 32), 256, 0, stream>>>(x, xsum);
  gemm_max_kernel<<<dim3(8, 512), 256, 0, stream>>>(x, W, ymax);

  rowdot_kernel<<<128, 256, 0, stream>>>(xsum, W, b, m1, 1.f / 2048.f);
  decode_kernel<<<128, 256, 0, stream>>>(ymax, b, amax);
  rowdot_kernel<<<128, 256, 0, stream>>>(m1, Wm, bm, t1, 1.f);
  rowdot_kernel<<<128, 256, 0, stream>>>(amax, Wa, ba, t2, 1.f);
  gn_kernel<<<64, 1024, 0, stream>>>(t1, t2, g1w, g1b, g2w, g2b, xM, xA);
  colmm_kernel<<<32, 256, 0, stream>>>(xM, xA, W1, u);         // u = W1^T (xM + xA)
  colmm_kernel<<<32, 256, 0, stream>>>(u, nullptr, W, vvec);   // v = W^T u
  logits_kernel<<<dim3(64, 32), 256, 0, stream>>>(x, vvec, sbuf);
  topk_kernel<<<32, 256, 0, stream>>>(sbuf, tidx);
  gather_kernel<<<640, 256, 0, stream>>>(x, tidx, Xsel);
  selgemm_kernel<<<dim3(16, 10), 256, 0, stream>>>(Xsel, W, b, Ysel);
  selgemm_kernel<<<dim3(16, 10), 256, 0, stream>>>(Ysel, W1, b1, (float*)d_out);
}

// Round 2
// 1217.351 us; speedup vs baseline: 1.0117x; 1.0117x over previous
//
#include <hip/hip_runtime.h>

#define L_SEQ 2048
#define CH    1024
#define NB    32
#define KSEL  20

typedef short v8s  __attribute__((ext_vector_type(8)));
typedef float v16f __attribute__((ext_vector_type(16)));

// ---------------- workspace layout (float offsets) ----------------
#define WS_XSUM   0          // [32*1024] f32   column sums of x
#define WS_YMAX   32768      // [32*1024] u32   encoded col-max of y
#define WS_M1     65536      // [32*1024] f32   mean-pool @ W^T + b
#define WS_AMAX   98304      // [32*1024] f32   decoded max-pool + b
#define WS_T1     131072     // [32*1024] f32
#define WS_T2     163840     // [32*1024] f32
#define WS_XM     196608     // [32*1024] f32
#define WS_XA     229376     // [32*1024] f32
#define WS_U      262144     // [32*1024] f32
#define WS_V      294912     // [32*1024] f32
#define WS_S      327680     // [32*2048] f32   logit sums
#define WS_TOPK   393216     // [640] int
#define WS_XSEL   393856     // [640*1024] f32
#define WS_YSEL   1049216    // [640*1024] f32
#define WS_WP     1704576    // [262144] uint4 view: packed W (hi/lo bf16 frag-major, 4 MB)

// ---------------- column means of x (atomic partial sums) ----------------
__global__ __launch_bounds__(256) void mean_kernel(const float* __restrict__ x,
                                                   float* __restrict__ xsum) {
  int b = blockIdx.y, chunk = blockIdx.x, t = threadIdx.x;
  const float4* bp = (const float4*)(x + ((size_t)b * L_SEQ + (size_t)chunk * 128) * CH);
  float sx = 0.f, sy = 0.f, sz = 0.f, sw = 0.f;
  #pragma unroll 4
  for (int l = 0; l < 128; ++l) {
    float4 a = bp[l * 256 + t];
    sx += a.x; sy += a.y; sz += a.z; sw += a.w;
  }
  float* dst = xsum + b * CH + t * 4;
  atomicAdd(dst + 0, sx); atomicAdd(dst + 1, sy);
  atomicAdd(dst + 2, sz); atomicAdd(dst + 3, sw);
}

// ---------------- fp32 -> (hi,lo) bf16 split, 8 elems -> two uint4 ----------------
__device__ __forceinline__ void split8(float4 qa, float4 qb, uint4& hi, uint4& lo) {
  float f[8] = {qa.x, qa.y, qa.z, qa.w, qb.x, qb.y, qb.z, qb.w};
  unsigned h[8], l[8];
  #pragma unroll
  for (int e = 0; e < 8; ++e) {
    unsigned u  = __float_as_uint(f[e]);
    unsigned hu = u & 0xFFFF0000u;                 // truncated hi bf16
    float lf    = f[e] - __uint_as_float(hu);      // residual
    h[e] = u >> 16;
    l[e] = __float_as_uint(lf) >> 16;              // truncated lo bf16
  }
  hi.x = h[0] | (h[1] << 16); hi.y = h[2] | (h[3] << 16);
  hi.z = h[4] | (h[5] << 16); hi.w = h[6] | (h[7] << 16);
  lo.x = l[0] | (l[1] << 16); lo.y = l[2] | (l[3] << 16);
  lo.z = l[4] | (l[5] << 16); lo.w = l[6] | (l[7] << 16);
}

// ---------------- pack W -> frag-major split-bf16 (hi/lo planes) ----------------
// chunk (Rw, kt) = 1024 uint4; slot = (mt*2 + s)*128 + c*32 + (r&31); lo at +64.
__global__ __launch_bounds__(256) void packw_kernel(const float* __restrict__ W,
                                                    uint4* __restrict__ wp) {
  int t = threadIdx.x, kt = blockIdx.x, Rw = blockIdx.y;
  const float* wb = W + (size_t)Rw * 128 * CH;
  uint4* out = wp + ((size_t)Rw * 32 + kt) * 1024;
  #pragma unroll
  for (int pass = 0; pass < 2; ++pass) {
    int idx = pass * 256 + t;           // 128 rows x 4 k-octet-pairs
    int r = idx >> 2, p = idx & 3;
    const float* ap = wb + (size_t)r * CH + kt * 32 + p * 8;
    float4 f0 = *(const float4*)ap;
    float4 f1 = *(const float4*)(ap + 4);
    uint4 hi, lo;
    split8(f0, f1, hi, lo);
    int slot = ((r >> 5) * 2 + (p >> 1)) * 128 + (p & 1) * 32 + (r & 31);
    out[slot] = hi;
    out[slot + 64] = lo;
  }
}

// ---------------- big GEMM (split-bf16 x3) + column max ----------------
// Block 256m x 128n, 4 waves (2 wm x 2 wn), wave tile 128m x 64n (Ti=4, Tj=2).
// A: f32 -> split -> LDS (frag-major). B: direct from packed global (L2-hot).
__global__ __launch_bounds__(256, 2) void gemm_max2(const float* __restrict__ X,
                                                    const uint4* __restrict__ wp,
                                                    unsigned* __restrict__ ymax) {
  __shared__ uint4 smA[2048];           // 32 KB: 8 mt x 2 s x {hi(64),lo(64)} x 16B
  const int t = threadIdx.x, lane = t & 63, wv = t >> 6;
  const int wm = wv >> 1, wn = wv & 1;
  const int nb = blockIdx.x;            // 0..7
  const int mb = blockIdx.y;            // 0..255
  const int batch = mb >> 3;
  const float* xb = X + (size_t)(mb * 256) * CH;

  v16f acc[4][2];
  #pragma unroll
  for (int i = 0; i < 4; ++i)
    #pragma unroll
    for (int j = 0; j < 2; ++j)
      #pragma unroll
      for (int e = 0; e < 16; ++e) acc[i][j][e] = 0.f;

  const uint4* wbase = wp + (size_t)nb * 32768 + lane;
  // B frag index (16B units): kt*1024 + ((mtw*2 + s)*2 + plane)*64, mtw = wn*2+j

  // ---- stage A tile for kt=0 ----
  {
    #pragma unroll
    for (int pass = 0; pass < 4; ++pass) {
      int idx = pass * 256 + t;
      int r = idx >> 2, p = idx & 3;
      const float* ap = xb + (size_t)r * CH + p * 8;
      float4 f0 = *(const float4*)ap;
      float4 f1 = *(const float4*)(ap + 4);
      uint4 hi, lo;
      split8(f0, f1, hi, lo);
      int slot = ((r >> 5) * 2 + (p >> 1)) * 128 + (p & 1) * 32 + (r & 31);
      smA[slot] = hi; smA[slot + 64] = lo;
    }
  }
  v8s bc[4], bn[4];
  #pragma unroll
  for (int j = 0; j < 2; ++j) {
    bc[j*2]   = *(const v8s*)&wbase[(((wn*2 + j)*2 + 0)*2 + 0) * 64];
    bc[j*2+1] = *(const v8s*)&wbase[(((wn*2 + j)*2 + 0)*2 + 1) * 64];
  }
  __syncthreads();

  for (int kt = 0; kt < 32; ++kt) {
    #pragma unroll
    for (int s = 0; s < 2; ++s) {
      const int nkt = s ? kt + 1 : kt;
      const int ns  = s ^ 1;
      if (nkt < 32) {
        #pragma unroll
        for (int j = 0; j < 2; ++j) {
          bn[j*2]   = *(const v8s*)&wbase[nkt * 1024 + (((wn*2 + j)*2 + ns)*2 + 0) * 64];
          bn[j*2+1] = *(const v8s*)&wbase[nkt * 1024 + (((wn*2 + j)*2 + ns)*2 + 1) * 64];
        }
      }
      v8s ah[4], al[4];
      #pragma unroll
      for (int i = 0; i < 4; ++i) {
        int base = ((wm * 4 + i) * 2 + s) * 128 + lane;
        ah[i] = *(const v8s*)&smA[base];
        al[i] = *(const v8s*)&smA[base + 64];
      }
      #pragma unroll
      for (int j = 0; j < 2; ++j) {
        v8s bh = bc[j*2], bl = bc[j*2+1];
        #pragma unroll
        for (int i = 0; i < 4; ++i) {
          acc[i][j] = __builtin_amdgcn_mfma_f32_32x32x16_bf16(ah[i], bh, acc[i][j], 0, 0, 0);
          acc[i][j] = __builtin_amdgcn_mfma_f32_32x32x16_bf16(ah[i], bl, acc[i][j], 0, 0, 0);
          acc[i][j] = __builtin_amdgcn_mfma_f32_32x32x16_bf16(al[i], bh, acc[i][j], 0, 0, 0);
        }
      }
      #pragma unroll
      for (int e = 0; e < 4; ++e) bc[e] = bn[e];
    }
    __syncthreads();
    if (kt < 31) {
      #pragma unroll
      for (int pass = 0; pass < 4; ++pass) {
        int idx = pass * 256 + t;
        int r = idx >> 2, p = idx & 3;
        const float* ap = xb + (size_t)r * CH + (kt + 1) * 32 + p * 8;
        float4 f0 = *(const float4*)ap;
        float4 f1 = *(const float4*)(ap + 4);
        uint4 hi, lo;
        split8(f0, f1, hi, lo);
        int slot = ((r >> 5) * 2 + (p >> 1)) * 128 + (p & 1) * 32 + (r & 31);
        smA[slot] = hi; smA[slot + 64] = lo;
      }
    }
    __syncthreads();
  }

  // column-max epilogue: 32x32 C/D layout, col = lane&31
  #pragma unroll
  for (int j = 0; j < 2; ++j) {
    float m = -INFINITY;
    #pragma unroll
    for (int i = 0; i < 4; ++i)
      #pragma unroll
      for (int e = 0; e < 16; ++e) m = fmaxf(m, acc[i][j][e]);
    m = fmaxf(m, __shfl_xor(m, 32));
    if (lane < 32) {
      int col = nb * 128 + wn * 64 + j * 32 + lane;
      unsigned u = __float_as_uint(m);
      unsigned enc = (m >= 0.f) ? (u | 0x80000000u) : ~u;  // order-preserving encode
      atomicMax(&ymax[batch * CH + col], enc);
    }
  }
}

// ---------------- decode encoded max + add linear bias ----------------
__global__ __launch_bounds__(256) void decode_kernel(const unsigned* __restrict__ ymax,
                                                     const float* __restrict__ bias,
                                                     float* __restrict__ amax) {
  int i = blockIdx.x * 256 + threadIdx.x;
  unsigned u = ymax[i];
  float f = (u & 0x80000000u) ? __uint_as_float(u & 0x7FFFFFFFu) : __uint_as_float(~u);
  amax[i] = f + bias[i & (CH - 1)];
}

// ---------------- O[b][d] = scale * sum_c I[b][c]*M[d][c] + bias[d] ----------------
__global__ __launch_bounds__(256) void rowdot_kernel(const float* __restrict__ I,
                                                     const float* __restrict__ M,
                                                     const float* __restrict__ bias,
                                                     float* __restrict__ O, float scale) {
  int t = threadIdx.x;
  int d = blockIdx.x * 8 + (t >> 5);
  int b = t & 31;
  const float4* Ir = (const float4*)(I + b * CH);
  const float4* Mr = (const float4*)(M + (size_t)d * CH);
  float acc = 0.f;
  #pragma unroll 4
  for (int c = 0; c < CH / 4; ++c) {
    float4 a = Ir[c], m = Mr[c];
    acc += a.x * m.x + a.y * m.y + a.z * m.z + a.w * m.w;
  }
  O[b * CH + d] = acc * scale + bias[d];
}

// ---------------- GroupNorm (32 groups of 32 channels), both branches ----------------
__global__ __launch_bounds__(1024) void gn_kernel(const float* __restrict__ t1, const float* __restrict__ t2,
                                                  const float* __restrict__ g1w, const float* __restrict__ g1b,
                                                  const float* __restrict__ g2w, const float* __restrict__ g2b,
                                                  float* __restrict__ xM, float* __restrict__ xA) {
  int which = blockIdx.x >> 5, b = blockIdx.x & 31, c = threadIdx.x;
  const float* in = which ? t2 : t1;
  const float* w  = which ? g2w : g1w;
  const float* bb = which ? g2b : g1b;
  float* out      = which ? xA : xM;
  float v = in[b * CH + c];
  float s = v;
  #pragma unroll
  for (int off = 16; off; off >>= 1) s += __shfl_xor(s, off);
  float mean = s * (1.f / 32.f);
  float d = v - mean;
  float ss = d * d;
  #pragma unroll
  for (int off = 16; off; off >>= 1) ss += __shfl_xor(ss, off);
  out[b * CH + c] = d * rsqrtf(ss * (1.f / 32.f) + 1e-5f) * w[c] + bb[c];
}

// ---------------- O[b][e] += sum_{c in chunk} (S1+S2)[b][c] * M[c][e] ----------------
__global__ __launch_bounds__(256) void colmm_kernel(const float* __restrict__ S1,
                                                    const float* __restrict__ S2,
                                                    const float* __restrict__ M,
                                                    float* __restrict__ O) {
  __shared__ float Sl[128][32];
  int t = threadIdx.x;
  int e0 = (blockIdx.x & 3) * 256, c0 = (blockIdx.x >> 2) * 128;
  for (int i = t; i < 4096; i += 256) {
    int c = i >> 5, b = i & 31;
    float val = S1[b * CH + c0 + c];
    if (S2) val += S2[b * CH + c0 + c];
    Sl[c][b] = val;
  }
  __syncthreads();
  int e = e0 + t;
  float acc[32];
  #pragma unroll
  for (int b = 0; b < 32; ++b) acc[b] = 0.f;
  for (int c = 0; c < 128; ++c) {
    float wv = M[(size_t)(c0 + c) * CH + e];
    #pragma unroll
    for (int b = 0; b < 32; ++b) acc[b] += Sl[c][b] * wv;
  }
  #pragma unroll
  for (int b = 0; b < 32; ++b) atomicAdd(&O[b * CH + e], acc[b]);
}

// ---------------- logits s[b][l] = x[b][l][:] . v[b][:] ----------------
__global__ __launch_bounds__(256) void logits_kernel(const float* __restrict__ x,
                                                     const float* __restrict__ v,
                                                     float* __restrict__ s) {
  __shared__ float4 vl[256];
  int b = blockIdx.y, chunk = blockIdx.x, t = threadIdx.x;
  vl[t] = ((const float4*)(v + b * CH))[t];
  __syncthreads();
  int wv = t >> 6, lane = t & 63;
  for (int it = 0; it < 8; ++it) {
    int l = chunk * 32 + it * 4 + wv;
    const float4* xr = (const float4*)(x + ((size_t)b * L_SEQ + l) * CH);
    float acc = 0.f;
    #pragma unroll
    for (int rep = 0; rep < 4; ++rep) {
      float4 a = xr[rep * 64 + lane];
      float4 c = vl[rep * 64 + lane];
      acc += a.x * c.x + a.y * c.y + a.z * c.z + a.w * c.w;
    }
    #pragma unroll
    for (int off = 32; off; off >>= 1) acc += __shfl_xor(acc, off);
    if (lane == 0) s[b * L_SEQ + l] = acc;
  }
}

// ---------------- top-20 (desc, ties -> lower index) ----------------
__global__ __launch_bounds__(256) void topk_kernel(const float* __restrict__ s,
                                                   int* __restrict__ idx_out) {
  int b = blockIdx.x, t = threadIdx.x;
  __shared__ float sv[L_SEQ];
  __shared__ float rv[256];
  __shared__ int   ri[256];
  for (int i = t; i < L_SEQ; i += 256) sv[i] = s[b * L_SEQ + i];
  __syncthreads();
  for (int k = 0; k < KSEL; ++k) {
    float bv = -INFINITY; int bi = 1 << 30;
    for (int i = t; i < L_SEQ; i += 256) {
      float v = sv[i];
      if (v > bv || (v == bv && i < bi)) { bv = v; bi = i; }
    }
    rv[t] = bv; ri[t] = bi; __syncthreads();
    for (int off = 128; off > 0; off >>= 1) {
      if (t < off) {
        float v2 = rv[t + off]; int i2 = ri[t + off];
        if (v2 > rv[t] || (v2 == rv[t] && i2 < ri[t])) { rv[t] = v2; ri[t] = i2; }
      }
      __syncthreads();
    }
    if (t == 0) { idx_out[b * KSEL + k] = ri[0]; sv[ri[0]] = -INFINITY; }
    __syncthreads();
  }
}

// ---------------- gather selected x rows ----------------
__global__ __launch_bounds__(256) void gather_kernel(const float* __restrict__ x,
                                                     const int* __restrict__ idx,
                                                     float* __restrict__ Xsel) {
  int row = blockIdx.x;          // 0..639
  int b = row / KSEL;
  int l = idx[row];
  const float4* src = (const float4*)(x + ((size_t)b * L_SEQ + l) * CH);
  float4* dst = (float4*)(Xsel + (size_t)row * CH);
  dst[threadIdx.x] = src[threadIdx.x];
}

// ---------------- exact fp32 GEMM for selected rows: C = A * B^T + bias ----------------
__global__ __launch_bounds__(256) void selgemm_kernel(const float* __restrict__ A,
                                                      const float* __restrict__ B,
                                                      const float* __restrict__ bias,
                                                      float* __restrict__ C) {
  __shared__ float As[64][17];
  __shared__ float Bs[64][17];
  int t = threadIdx.x;
  int tx = t & 15, ty = t >> 4;
  int n0 = blockIdx.x * 64, m0 = blockIdx.y * 64;
  float acc[4][4];
  #pragma unroll
  for (int i = 0; i < 4; ++i)
    #pragma unroll
    for (int j = 0; j < 4; ++j) acc[i][j] = 0.f;
  for (int k0 = 0; k0 < CH; k0 += 16) {
    #pragma unroll
    for (int j = 0; j < 4; ++j) {
      int e = t * 4 + j;
      int row = e >> 4, kk = e & 15;
      As[row][kk] = A[(size_t)(m0 + row) * CH + k0 + kk];
      Bs[row][kk] = B[(size_t)(n0 + row) * CH + k0 + kk];
    }
    __syncthreads();
    #pragma unroll
    for (int kk = 0; kk < 16; ++kk) {
      float a[4], bb[4];
      #pragma unroll
      for (int i = 0; i < 4; ++i) a[i] = As[ty * 4 + i][kk];
      #pragma unroll
      for (int j = 0; j < 4; ++j) bb[j] = Bs[tx * 4 + j][kk];
      #pragma unroll
      for (int i = 0; i < 4; ++i)
        #pragma unroll
        for (int j = 0; j < 4; ++j) acc[i][j] += a[i] * bb[j];
    }
    __syncthreads();
  }
  #pragma unroll
  for (int i = 0; i < 4; ++i)
    #pragma unroll
    for (int j = 0; j < 4; ++j)
      C[(size_t)(m0 + ty * 4 + i) * CH + n0 + tx * 4 + j] = acc[i][j] + bias[n0 + tx * 4 + j];
}

extern "C" void kernel_launch(void* const* d_in, const int* in_sizes, int n_in,
                              void* d_out, int out_size, void* d_ws, size_t ws_size,
                              hipStream_t stream) {
  const float* x   = (const float*)d_in[0];
  const float* W   = (const float*)d_in[1];
  const float* b   = (const float*)d_in[2];
  const float* W1  = (const float*)d_in[3];
  const float* b1  = (const float*)d_in[4];
  const float* Wm  = (const float*)d_in[5];
  const float* bm  = (const float*)d_in[6];
  const float* Wa  = (const float*)d_in[7];
  const float* ba  = (const float*)d_in[8];
  const float* g1w = (const float*)d_in[9];
  const float* g1b = (const float*)d_in[10];
  const float* g2w = (const float*)d_in[11];
  const float* g2b = (const float*)d_in[12];

  float* wsf = (float*)d_ws;
  float*    xsum = wsf + WS_XSUM;
  unsigned* ymax = (unsigned*)(wsf + WS_YMAX);
  float*    m1   = wsf + WS_M1;
  float*    amax = wsf + WS_AMAX;
  float*    t1   = wsf + WS_T1;
  float*    t2   = wsf + WS_T2;
  float*    xM   = wsf + WS_XM;
  float*    xA   = wsf + WS_XA;
  float*    u    = wsf + WS_U;
  float*    vvec = wsf + WS_V;
  float*    sbuf = wsf + WS_S;
  int*      tidx = (int*)(wsf + WS_TOPK);
  float*    Xsel = wsf + WS_XSEL;
  float*    Ysel = wsf + WS_YSEL;
  uint4*    wpak = (uint4*)(wsf + WS_WP);

  hipMemsetAsync(wsf + WS_XSUM, 0, 65536 * sizeof(float), stream);
  hipMemsetAsync(wsf + WS_U,    0, 65536 * sizeof(float), stream);

  packw_kernel<<<dim3(32, 8), 256, 0, stream>>>(W, wpak);
  mean_kernel<<<dim3(16, 32), 256, 0, stream>>>(x, xsum);
  gemm_max2<<<dim3(8, 256), 256, 0, stream>>>(x, wpak, ymax);

  rowdot_kernel<<<128, 256, 0, stream>>>(xsum, W, b, m1, 1.f / 2048.f);
  decode_kernel<<<128, 256, 0, stream>>>(ymax, b, amax);
  rowdot_kernel<<<128, 256, 0, stream>>>(m1, Wm, bm, t1, 1.f);
  rowdot_kernel<<<128, 256, 0, stream>>>(amax, Wa, ba, t2, 1.f);
  gn_kernel<<<64, 1024, 0, stream>>>(t1, t2, g1w, g1b, g2w, g2b, xM, xA);
  colmm_kernel<<<32, 256, 0, stream>>>(xM, xA, W1, u);         // u = W1^T (xM + xA)
  colmm_kernel<<<32, 256, 0, stream>>>(u, nullptr, W, vvec);   // v = W^T u
  logits_kernel<<<dim3(64, 32), 256, 0, stream>>>(x, vvec, sbuf);
  topk_kernel<<<32, 256, 0, stream>>>(sbuf, tidx);
  gather_kernel<<<640, 256, 0, stream>>>(x, tidx, Xsel);
  selgemm_kernel<<<dim3(16, 10), 256, 0, stream>>>(Xsel, W, b, Ysel);
  selgemm_kernel<<<dim3(16, 10), 256, 0, stream>>>(Ysel, W1, b1, (float*)d_out);
}

// Round 3
// 1192.271 us; speedup vs baseline: 1.0330x; 1.0210x over previous
//
#include <hip/hip_runtime.h>

#define L_SEQ 2048
#define CH    1024
#define NB    32
#define KSEL  20

typedef short v8s  __attribute__((ext_vector_type(8)));
typedef float v16f __attribute__((ext_vector_type(16)));

// ---------------- workspace layout (float offsets) ----------------
#define WS_XSUM   0          // [32*1024] f32   column sums of x
#define WS_YMAX   32768      // [32*1024] u32   encoded col-max of y
#define WS_M1     65536      // [32*1024] f32   mean-pool @ W^T + b
#define WS_AMAX   98304      // [32*1024] f32   decoded max-pool + b
#define WS_T1     131072     // [32*1024] f32
#define WS_T2     163840     // [32*1024] f32
#define WS_XM     196608     // [32*1024] f32
#define WS_XA     229376     // [32*1024] f32
#define WS_U      262144     // [32*1024] f32
#define WS_V      294912     // [32*1024] f32
#define WS_S      327680     // [32*2048] f32   logit sums
#define WS_TOPK   393216     // [640] int
#define WS_XSEL   393856     // [640*1024] f32
#define WS_YSEL   1049216    // [640*1024] f32
#define WS_WP     1704576    // [262144] uint4 view: packed W (hi/lo bf16 frag-major, 4 MB)

// ---------------- column means of x (atomic partial sums) ----------------
__global__ __launch_bounds__(256) void mean_kernel(const float* __restrict__ x,
                                                   float* __restrict__ xsum) {
  int b = blockIdx.y, chunk = blockIdx.x, t = threadIdx.x;
  const float4* bp = (const float4*)(x + ((size_t)b * L_SEQ + (size_t)chunk * 128) * CH);
  float sx = 0.f, sy = 0.f, sz = 0.f, sw = 0.f;
  #pragma unroll 4
  for (int l = 0; l < 128; ++l) {
    float4 a = bp[l * 256 + t];
    sx += a.x; sy += a.y; sz += a.z; sw += a.w;
  }
  float* dst = xsum + b * CH + t * 4;
  atomicAdd(dst + 0, sx); atomicAdd(dst + 1, sy);
  atomicAdd(dst + 2, sz); atomicAdd(dst + 3, sw);
}

// ---------------- fp32 -> (hi,lo) bf16 split, 8 elems -> two uint4 ----------------
__device__ __forceinline__ void split8(float4 qa, float4 qb, uint4& hi, uint4& lo) {
  float f[8] = {qa.x, qa.y, qa.z, qa.w, qb.x, qb.y, qb.z, qb.w};
  unsigned h[8], l[8];
  #pragma unroll
  for (int e = 0; e < 8; ++e) {
    unsigned u  = __float_as_uint(f[e]);
    unsigned hu = u & 0xFFFF0000u;                 // truncated hi bf16
    float lf    = f[e] - __uint_as_float(hu);      // residual
    h[e] = u >> 16;
    l[e] = __float_as_uint(lf) >> 16;              // truncated lo bf16
  }
  hi.x = h[0] | (h[1] << 16); hi.y = h[2] | (h[3] << 16);
  hi.z = h[4] | (h[5] << 16); hi.w = h[6] | (h[7] << 16);
  lo.x = l[0] | (l[1] << 16); lo.y = l[2] | (l[3] << 16);
  lo.z = l[4] | (l[5] << 16); lo.w = l[6] | (l[7] << 16);
}

// ---------------- pack W -> frag-major split-bf16 (hi/lo planes) ----------------
// chunk (Rw, kt) = 1024 uint4; region(colgrp,s) = 128 slots [hi 64 | lo 64],
// hi slot within region = (p&1)*32 + (r&31)  (== lane order col=lane&31, oct=lane>>5)
__global__ __launch_bounds__(256) void packw_kernel(const float* __restrict__ W,
                                                    uint4* __restrict__ wp) {
  int t = threadIdx.x, kt = blockIdx.x, Rw = blockIdx.y;
  const float* wb = W + (size_t)Rw * 128 * CH;
  uint4* out = wp + ((size_t)Rw * 32 + kt) * 1024;
  #pragma unroll
  for (int pass = 0; pass < 2; ++pass) {
    int idx = pass * 256 + t;           // 128 rows x 4 k-octet-pairs
    int r = idx >> 2, p = idx & 3;
    const float* ap = wb + (size_t)r * CH + kt * 32 + p * 8;
    float4 f0 = *(const float4*)ap;
    float4 f1 = *(const float4*)(ap + 4);
    uint4 hi, lo;
    split8(f0, f1, hi, lo);
    int slot = ((r >> 5) * 2 + (p >> 1)) * 128 + (p & 1) * 32 + (r & 31);
    out[slot] = hi;
    out[slot + 64] = lo;
  }
}

// ---------------- big GEMM (split-bf16 x3) + column max ----------------
// 512 thr (8 waves = 4wm x 2wn), block 256m x 256n, wave 64m x 128n.
// A: f32 -> split -> LDS, conflict-free (consecutive-slot stores), double-buffered.
// B: direct from packed global (L1/L2-hot). Grid flat: nb = blk&3 (XCD-pins B strip).
__global__ __launch_bounds__(512, 2) void gemm_max3(const float* __restrict__ X,
                                                    const uint4* __restrict__ wp,
                                                    unsigned* __restrict__ ymax) {
  __shared__ uint4 smA[2][2048];        // 64 KB: [buf][region(mt,s)*128 + plane*64 + lane]
  const int t = threadIdx.x, lane = t & 63, w = t >> 6;
  const int wm = w >> 1, wn = w & 1;
  const int blk = blockIdx.x;
  const int nb = blk & 3, mb = blk >> 2;
  const int batch = mb >> 3;            // 8 blocks of 256 rows per batch
  const float* xb = X + (size_t)mb * 256 * CH;

  // staging identity: wave w stages region mt=w for s=0,1
  const int srow = w * 32 + (lane & 31);
  const int koct = lane >> 5;
  const float* arow = xb + (size_t)srow * CH + koct * 8;

  v16f acc[2][4];
  #pragma unroll
  for (int i = 0; i < 2; ++i)
    #pragma unroll
    for (int j = 0; j < 4; ++j)
      #pragma unroll
      for (int e = 0; e < 16; ++e) acc[i][j][e] = 0.f;

  const uint4* wbB = wp + ((size_t)(nb * 2 + wn)) * 32768 + lane;
  // B slot offset for (kt, j, s, plane): kt*1024 + ((j*2+s)*2 + plane)*64

  // ---- stage kt=0 into buf 0 ----
  {
    float4 p0 = *(const float4*)(arow);
    float4 p1 = *(const float4*)(arow + 4);
    float4 p2 = *(const float4*)(arow + 16);
    float4 p3 = *(const float4*)(arow + 20);
    uint4 hi, lo;
    split8(p0, p1, hi, lo);
    smA[0][(w * 2 + 0) * 128 + lane] = hi;
    smA[0][(w * 2 + 0) * 128 + 64 + lane] = lo;
    split8(p2, p3, hi, lo);
    smA[0][(w * 2 + 1) * 128 + lane] = hi;
    smA[0][(w * 2 + 1) * 128 + 64 + lane] = lo;
  }
  // ---- prefetch B (kt=0, s=0) ----
  v8s bc[8], bn[8];
  #pragma unroll
  for (int j = 0; j < 4; ++j) {
    bc[j * 2]     = *(const v8s*)&wbB[((j * 2 + 0) * 2 + 0) * 64];
    bc[j * 2 + 1] = *(const v8s*)&wbB[((j * 2 + 0) * 2 + 1) * 64];
  }
  __syncthreads();

  for (int kt = 0; kt < 32; ++kt) {
    const int cur = kt & 1;
    float4 q0, q1, q2, q3;
    if (kt < 31) {                      // issue next A-slice loads early
      const float* an = arow + (kt + 1) * 32;
      q0 = *(const float4*)(an);
      q1 = *(const float4*)(an + 4);
      q2 = *(const float4*)(an + 16);
      q3 = *(const float4*)(an + 20);
    }
    #pragma unroll
    for (int s = 0; s < 2; ++s) {
      const int nkt = s ? kt + 1 : kt, ns = s ^ 1;
      if (nkt < 32) {                   // prefetch next B half-slice
        #pragma unroll
        for (int j = 0; j < 4; ++j) {
          bn[j * 2]     = *(const v8s*)&wbB[(size_t)nkt * 1024 + ((j * 2 + ns) * 2 + 0) * 64];
          bn[j * 2 + 1] = *(const v8s*)&wbB[(size_t)nkt * 1024 + ((j * 2 + ns) * 2 + 1) * 64];
        }
      }
      v8s ah[2], al[2];
      #pragma unroll
      for (int i = 0; i < 2; ++i) {
        int base = ((wm * 2 + i) * 2 + s) * 128 + lane;
        ah[i] = *(const v8s*)&smA[cur][base];
        al[i] = *(const v8s*)&smA[cur][base + 64];
      }
      #pragma unroll
      for (int j = 0; j < 4; ++j) {
        v8s bh = bc[j * 2], bl = bc[j * 2 + 1];
        #pragma unroll
        for (int i = 0; i < 2; ++i) {
          acc[i][j] = __builtin_amdgcn_mfma_f32_32x32x16_bf16(ah[i], bh, acc[i][j], 0, 0, 0);
          acc[i][j] = __builtin_amdgcn_mfma_f32_32x32x16_bf16(ah[i], bl, acc[i][j], 0, 0, 0);
          acc[i][j] = __builtin_amdgcn_mfma_f32_32x32x16_bf16(al[i], bh, acc[i][j], 0, 0, 0);
        }
      }
      #pragma unroll
      for (int e = 0; e < 8; ++e) bc[e] = bn[e];
    }
    if (kt < 31) {                      // split + store kt+1 into other buf
      uint4 hi, lo;
      split8(q0, q1, hi, lo);
      smA[cur ^ 1][(w * 2 + 0) * 128 + lane] = hi;
      smA[cur ^ 1][(w * 2 + 0) * 128 + 64 + lane] = lo;
      split8(q2, q3, hi, lo);
      smA[cur ^ 1][(w * 2 + 1) * 128 + lane] = hi;
      smA[cur ^ 1][(w * 2 + 1) * 128 + 64 + lane] = lo;
    }
    __syncthreads();
  }

  // column-max epilogue: 32x32 C/D layout, col = lane&31
  #pragma unroll
  for (int j = 0; j < 4; ++j) {
    float m = -INFINITY;
    #pragma unroll
    for (int i = 0; i < 2; ++i)
      #pragma unroll
      for (int e = 0; e < 16; ++e) m = fmaxf(m, acc[i][j][e]);
    m = fmaxf(m, __shfl_xor(m, 32));
    if (lane < 32) {
      int col = nb * 256 + wn * 128 + j * 32 + lane;
      unsigned u = __float_as_uint(m);
      unsigned enc = (m >= 0.f) ? (u | 0x80000000u) : ~u;  // order-preserving encode
      atomicMax(&ymax[batch * CH + col], enc);
    }
  }
}

// ---------------- decode encoded max + add linear bias ----------------
__global__ __launch_bounds__(256) void decode_kernel(const unsigned* __restrict__ ymax,
                                                     const float* __restrict__ bias,
                                                     float* __restrict__ amax) {
  int i = blockIdx.x * 256 + threadIdx.x;
  unsigned u = ymax[i];
  float f = (u & 0x80000000u) ? __uint_as_float(u & 0x7FFFFFFFu) : __uint_as_float(~u);
  amax[i] = f + bias[i & (CH - 1)];
}

// ---------------- O[b][d] = scale * sum_c I[b][c]*M[d][c] + bias[d] ----------------
__global__ __launch_bounds__(256) void rowdot_kernel(const float* __restrict__ I,
                                                     const float* __restrict__ M,
                                                     const float* __restrict__ bias,
                                                     float* __restrict__ O, float scale) {
  int t = threadIdx.x;
  int d = blockIdx.x * 8 + (t >> 5);
  int b = t & 31;
  const float4* Ir = (const float4*)(I + b * CH);
  const float4* Mr = (const float4*)(M + (size_t)d * CH);
  float acc = 0.f;
  #pragma unroll 4
  for (int c = 0; c < CH / 4; ++c) {
    float4 a = Ir[c], m = Mr[c];
    acc += a.x * m.x + a.y * m.y + a.z * m.z + a.w * m.w;
  }
  O[b * CH + d] = acc * scale + bias[d];
}

// ---------------- GroupNorm (32 groups of 32 channels), both branches ----------------
__global__ __launch_bounds__(1024) void gn_kernel(const float* __restrict__ t1, const float* __restrict__ t2,
                                                  const float* __restrict__ g1w, const float* __restrict__ g1b,
                                                  const float* __restrict__ g2w, const float* __restrict__ g2b,
                                                  float* __restrict__ xM, float* __restrict__ xA) {
  int which = blockIdx.x >> 5, b = blockIdx.x & 31, c = threadIdx.x;
  const float* in = which ? t2 : t1;
  const float* w  = which ? g2w : g1w;
  const float* bb = which ? g2b : g1b;
  float* out      = which ? xA : xM;
  float v = in[b * CH + c];
  float s = v;
  #pragma unroll
  for (int off = 16; off; off >>= 1) s += __shfl_xor(s, off);
  float mean = s * (1.f / 32.f);
  float d = v - mean;
  float ss = d * d;
  #pragma unroll
  for (int off = 16; off; off >>= 1) ss += __shfl_xor(ss, off);
  out[b * CH + c] = d * rsqrtf(ss * (1.f / 32.f) + 1e-5f) * w[c] + bb[c];
}

// ---------------- O[b][e] += sum_{c in chunk} (S1+S2)[b][c] * M[c][e] ----------------
__global__ __launch_bounds__(256) void colmm_kernel(const float* __restrict__ S1,
                                                    const float* __restrict__ S2,
                                                    const float* __restrict__ M,
                                                    float* __restrict__ O) {
  __shared__ float Sl[128][32];
  int t = threadIdx.x;
  int e0 = (blockIdx.x & 3) * 256, c0 = (blockIdx.x >> 2) * 128;
  for (int i = t; i < 4096; i += 256) {
    int c = i >> 5, b = i & 31;
    float val = S1[b * CH + c0 + c];
    if (S2) val += S2[b * CH + c0 + c];
    Sl[c][b] = val;
  }
  __syncthreads();
  int e = e0 + t;
  float acc[32];
  #pragma unroll
  for (int b = 0; b < 32; ++b) acc[b] = 0.f;
  for (int c = 0; c < 128; ++c) {
    float wv = M[(size_t)(c0 + c) * CH + e];
    #pragma unroll
    for (int b = 0; b < 32; ++b) acc[b] += Sl[c][b] * wv;
  }
  #pragma unroll
  for (int b = 0; b < 32; ++b) atomicAdd(&O[b * CH + e], acc[b]);
}

// ---------------- logits s[b][l] = x[b][l][:] . v[b][:] ----------------
__global__ __launch_bounds__(256) void logits_kernel(const float* __restrict__ x,
                                                     const float* __restrict__ v,
                                                     float* __restrict__ s) {
  __shared__ float4 vl[256];
  int b = blockIdx.y, chunk = blockIdx.x, t = threadIdx.x;
  vl[t] = ((const float4*)(v + b * CH))[t];
  __syncthreads();
  int wv = t >> 6, lane = t & 63;
  for (int it = 0; it < 8; ++it) {
    int l = chunk * 32 + it * 4 + wv;
    const float4* xr = (const float4*)(x + ((size_t)b * L_SEQ + l) * CH);
    float acc = 0.f;
    #pragma unroll
    for (int rep = 0; rep < 4; ++rep) {
      float4 a = xr[rep * 64 + lane];
      float4 c = vl[rep * 64 + lane];
      acc += a.x * c.x + a.y * c.y + a.z * c.z + a.w * c.w;
    }
    #pragma unroll
    for (int off = 32; off; off >>= 1) acc += __shfl_xor(acc, off);
    if (lane == 0) s[b * L_SEQ + l] = acc;
  }
}

// ---------------- top-20 (desc, ties -> lower index) ----------------
__global__ __launch_bounds__(256) void topk_kernel(const float* __restrict__ s,
                                                   int* __restrict__ idx_out) {
  int b = blockIdx.x, t = threadIdx.x;
  __shared__ float sv[L_SEQ];
  __shared__ float rv[256];
  __shared__ int   ri[256];
  for (int i = t; i < L_SEQ; i += 256) sv[i] = s[b * L_SEQ + i];
  __syncthreads();
  for (int k = 0; k < KSEL; ++k) {
    float bv = -INFINITY; int bi = 1 << 30;
    for (int i = t; i < L_SEQ; i += 256) {
      float v = sv[i];
      if (v > bv || (v == bv && i < bi)) { bv = v; bi = i; }
    }
    rv[t] = bv; ri[t] = bi; __syncthreads();
    for (int off = 128; off > 0; off >>= 1) {
      if (t < off) {
        float v2 = rv[t + off]; int i2 = ri[t + off];
        if (v2 > rv[t] || (v2 == rv[t] && i2 < ri[t])) { rv[t] = v2; ri[t] = i2; }
      }
      __syncthreads();
    }
    if (t == 0) { idx_out[b * KSEL + k] = ri[0]; sv[ri[0]] = -INFINITY; }
    __syncthreads();
  }
}

// ---------------- gather selected x rows ----------------
__global__ __launch_bounds__(256) void gather_kernel(const float* __restrict__ x,
                                                     const int* __restrict__ idx,
                                                     float* __restrict__ Xsel) {
  int row = blockIdx.x;          // 0..639
  int b = row / KSEL;
  int l = idx[row];
  const float4* src = (const float4*)(x + ((size_t)b * L_SEQ + l) * CH);
  float4* dst = (float4*)(Xsel + (size_t)row * CH);
  dst[threadIdx.x] = src[threadIdx.x];
}

// ---------------- exact fp32 GEMM for selected rows: C = A * B^T + bias ----------------
__global__ __launch_bounds__(256) void selgemm_kernel(const float* __restrict__ A,
                                                      const float* __restrict__ B,
                                                      const float* __restrict__ bias,
                                                      float* __restrict__ C) {
  __shared__ float As[64][17];
  __shared__ float Bs[64][17];
  int t = threadIdx.x;
  int tx = t & 15, ty = t >> 4;
  int n0 = blockIdx.x * 64, m0 = blockIdx.y * 64;
  float acc[4][4];
  #pragma unroll
  for (int i = 0; i < 4; ++i)
    #pragma unroll
    for (int j = 0; j < 4; ++j) acc[i][j] = 0.f;
  for (int k0 = 0; k0 < CH; k0 += 16) {
    #pragma unroll
    for (int j = 0; j < 4; ++j) {
      int e = t * 4 + j;
      int row = e >> 4, kk = e & 15;
      As[row][kk] = A[(size_t)(m0 + row) * CH + k0 + kk];
      Bs[row][kk] = B[(size_t)(n0 + row) * CH + k0 + kk];
    }
    __syncthreads();
    #pragma unroll
    for (int kk = 0; kk < 16; ++kk) {
      float a[4], bb[4];
      #pragma unroll
      for (int i = 0; i < 4; ++i) a[i] = As[ty * 4 + i][kk];
      #pragma unroll
      for (int j = 0; j < 4; ++j) bb[j] = Bs[tx * 4 + j][kk];
      #pragma unroll
      for (int i = 0; i < 4; ++i)
        #pragma unroll
        for (int j = 0; j < 4; ++j) acc[i][j] += a[i] * bb[j];
    }
    __syncthreads();
  }
  #pragma unroll
  for (int i = 0; i < 4; ++i)
    #pragma unroll
    for (int j = 0; j < 4; ++j)
      C[(size_t)(m0 + ty * 4 + i) * CH + n0 + tx * 4 + j] = acc[i][j] + bias[n0 + tx * 4 + j];
}

extern "C" void kernel_launch(void* const* d_in, const int* in_sizes, int n_in,
                              void* d_out, int out_size, void* d_ws, size_t ws_size,
                              hipStream_t stream) {
  const float* x   = (const float*)d_in[0];
  const float* W   = (const float*)d_in[1];
  const float* b   = (const float*)d_in[2];
  const float* W1  = (const float*)d_in[3];
  const float* b1  = (const float*)d_in[4];
  const float* Wm  = (const float*)d_in[5];
  const float* bm  = (const float*)d_in[6];
  const float* Wa  = (const float*)d_in[7];
  const float* ba  = (const float*)d_in[8];
  const float* g1w = (const float*)d_in[9];
  const float* g1b = (const float*)d_in[10];
  const float* g2w = (const float*)d_in[11];
  const float* g2b = (const float*)d_in[12];

  float* wsf = (float*)d_ws;
  float*    xsum = wsf + WS_XSUM;
  unsigned* ymax = (unsigned*)(wsf + WS_YMAX);
  float*    m1   = wsf + WS_M1;
  float*    amax = wsf + WS_AMAX;
  float*    t1   = wsf + WS_T1;
  float*    t2   = wsf + WS_T2;
  float*    xM   = wsf + WS_XM;
  float*    xA   = wsf + WS_XA;
  float*    u    = wsf + WS_U;
  float*    vvec = wsf + WS_V;
  float*    sbuf = wsf + WS_S;
  int*      tidx = (int*)(wsf + WS_TOPK);
  float*    Xsel = wsf + WS_XSEL;
  float*    Ysel = wsf + WS_YSEL;
  uint4*    wpak = (uint4*)(wsf + WS_WP);

  hipMemsetAsync(wsf + WS_XSUM, 0, 65536 * sizeof(float), stream);
  hipMemsetAsync(wsf + WS_U,    0, 65536 * sizeof(float), stream);

  packw_kernel<<<dim3(32, 8), 256, 0, stream>>>(W, wpak);
  mean_kernel<<<dim3(16, 32), 256, 0, stream>>>(x, xsum);
  gemm_max3<<<1024, 512, 0, stream>>>(x, wpak, ymax);

  rowdot_kernel<<<128, 256, 0, stream>>>(xsum, W, b, m1, 1.f / 2048.f);
  decode_kernel<<<128, 256, 0, stream>>>(ymax, b, amax);
  rowdot_kernel<<<128, 256, 0, stream>>>(m1, Wm, bm, t1, 1.f);
  rowdot_kernel<<<128, 256, 0, stream>>>(amax, Wa, ba, t2, 1.f);
  gn_kernel<<<64, 1024, 0, stream>>>(t1, t2, g1w, g1b, g2w, g2b, xM, xA);
  colmm_kernel<<<32, 256, 0, stream>>>(xM, xA, W1, u);         // u = W1^T (xM + xA)
  colmm_kernel<<<32, 256, 0, stream>>>(u, nullptr, W, vvec);   // v = W^T u
  logits_kernel<<<dim3(64, 32), 256, 0, stream>>>(x, vvec, sbuf);
  topk_kernel<<<32, 256, 0, stream>>>(sbuf, tidx);
  gather_kernel<<<640, 256, 0, stream>>>(x, tidx, Xsel);
  selgemm_kernel<<<dim3(16, 10), 256, 0, stream>>>(Xsel, W, b, Ysel);
  selgemm_kernel<<<dim3(16, 10), 256, 0, stream>>>(Ysel, W1, b1, (float*)d_out);
}

// Round 4
// 1097.745 us; speedup vs baseline: 1.1220x; 1.0861x over previous
//
#include <hip/hip_runtime.h>

#define L_SEQ 2048
#define CH    1024
#define NB    32
#define KSEL  20

typedef short v8s  __attribute__((ext_vector_type(8)));
typedef float v16f __attribute__((ext_vector_type(16)));

// ---------------- workspace layout (float offsets) ----------------
#define WS_XSUM   0          // [32*1024] f32   column sums of x
#define WS_YMAX   32768      // [32*1024] u32   encoded col-max of y
#define WS_M1     65536      // [32*1024] f32   mean-pool @ W^T + b
#define WS_AMAX   98304      // [32*1024] f32   decoded max-pool + b
#define WS_T1     131072     // [32*1024] f32
#define WS_T2     163840     // [32*1024] f32
#define WS_P      196608     // [32*1024] f32   gn1(t1)+gn2(t2)
#define WS_U      262144     // [32*1024] f32
#define WS_V      294912     // [32*1024] f32
#define WS_S      327680     // [32*2048] f32   logit sums
#define WS_TOPK   393216     // [640] int
#define WS_YSEL   1049216    // [640*1024] f32
#define WS_WP     1704576    // [262144] uint4 view: packed W (hi/lo bf16 frag-major, 4 MB)

// ---------------- fp32 -> (hi,lo) bf16 split, 8 elems -> two uint4 ----------------
__device__ __forceinline__ void split8(float4 qa, float4 qb, uint4& hi, uint4& lo) {
  float f[8] = {qa.x, qa.y, qa.z, qa.w, qb.x, qb.y, qb.z, qb.w};
  unsigned h[8], l[8];
  #pragma unroll
  for (int e = 0; e < 8; ++e) {
    unsigned u  = __float_as_uint(f[e]);
    unsigned hu = u & 0xFFFF0000u;                 // truncated hi bf16
    float lf    = f[e] - __uint_as_float(hu);      // residual
    h[e] = u >> 16;
    l[e] = __float_as_uint(lf) >> 16;              // truncated lo bf16
  }
  hi.x = h[0] | (h[1] << 16); hi.y = h[2] | (h[3] << 16);
  hi.z = h[4] | (h[5] << 16); hi.w = h[6] | (h[7] << 16);
  lo.x = l[0] | (l[1] << 16); lo.y = l[2] | (l[3] << 16);
  lo.z = l[4] | (l[5] << 16); lo.w = l[6] | (l[7] << 16);
}

// ---------------- pack W -> frag-major split-bf16; also zero-init accumulators ----
__global__ __launch_bounds__(256) void packw_kernel(const float* __restrict__ W,
                                                    uint4* __restrict__ wp,
                                                    float* __restrict__ wsf) {
  int t = threadIdx.x, kt = blockIdx.x, Rw = blockIdx.y;
  // fold the two memsets in: zero xsum+ymax (65536 f) and u+v (65536 f)
  int flat = (Rw * 32 + kt) * 256 + t;             // 0..65535
  wsf[WS_XSUM + flat] = 0.f;
  wsf[WS_U + flat]    = 0.f;
  const float* wb = W + (size_t)Rw * 128 * CH;
  uint4* out = wp + ((size_t)Rw * 32 + kt) * 1024;
  #pragma unroll
  for (int pass = 0; pass < 2; ++pass) {
    int idx = pass * 256 + t;           // 128 rows x 4 k-octet-pairs
    int r = idx >> 2, p = idx & 3;
    const float* ap = wb + (size_t)r * CH + kt * 32 + p * 8;
    float4 f0 = *(const float4*)ap;
    float4 f1 = *(const float4*)(ap + 4);
    uint4 hi, lo;
    split8(f0, f1, hi, lo);
    int slot = ((r >> 5) * 2 + (p >> 1)) * 128 + (p & 1) * 32 + (r & 31);
    out[slot] = hi;
    out[slot + 64] = lo;
  }
}

// ---------------- column means of x (atomic partial sums) ----------------
__global__ __launch_bounds__(256) void mean_kernel(const float* __restrict__ x,
                                                   float* __restrict__ xsum) {
  int b = blockIdx.y, chunk = blockIdx.x, t = threadIdx.x;
  const float4* bp = (const float4*)(x + ((size_t)b * L_SEQ + (size_t)chunk * 64) * CH);
  float sx = 0.f, sy = 0.f, sz = 0.f, sw = 0.f;
  #pragma unroll 4
  for (int l = 0; l < 64; ++l) {
    float4 a = bp[l * 256 + t];
    sx += a.x; sy += a.y; sz += a.z; sw += a.w;
  }
  float* dst = xsum + b * CH + t * 4;
  atomicAdd(dst + 0, sx); atomicAdd(dst + 1, sy);
  atomicAdd(dst + 2, sz); atomicAdd(dst + 3, sw);
}

// ---------------- big GEMM (split-bf16 x3) + column max ----------------
// 256 thr (4 waves = 2wm x 2wn), block 128m x 256n, wave 64m x 128n.
// 2 blocks/CU (LDS 32KB, regs ~248 -> 8 waves/CU) so barrier drains overlap.
__global__ __launch_bounds__(256, 2) void gemm_max4(const float* __restrict__ X,
                                                    const uint4* __restrict__ wp,
                                                    unsigned* __restrict__ ymax) {
  __shared__ uint4 smA[2][1024];        // 32 KB: [buf][region(mt,s)*128 + plane*64 + lane]
  const int t = threadIdx.x, lane = t & 63, w = t >> 6;
  const int wm = w >> 1, wn = w & 1;
  const int blk = blockIdx.x;
  const int strip = blk & 3, mt = blk >> 2;    // strip: 256 cols; mt: 128 rows
  const int batch = mt >> 4;                   // 16 m-tiles per batch
  const float* xb = X + (size_t)mt * 128 * CH;

  // staging identity: wave w stages rows w*32..w*32+31 (regions w*2, w*2+1)
  const int srow = w * 32 + (lane & 31);
  const int koct = lane >> 5;
  const float* arow = xb + (size_t)srow * CH + koct * 8;

  v16f acc[2][4];
  #pragma unroll
  for (int i = 0; i < 2; ++i)
    #pragma unroll
    for (int j = 0; j < 4; ++j)
      #pragma unroll
      for (int e = 0; e < 16; ++e) acc[i][j][e] = 0.f;

  const uint4* wbB = wp + ((size_t)(strip * 2 + wn)) * 32768 + lane;
  // B slot offset for (kt, j, s, plane): kt*1024 + ((j*2+s)*2 + plane)*64

  // ---- stage kt=0 into buf 0 ----
  {
    float4 p0 = *(const float4*)(arow);
    float4 p1 = *(const float4*)(arow + 4);
    float4 p2 = *(const float4*)(arow + 16);
    float4 p3 = *(const float4*)(arow + 20);
    uint4 hi, lo;
    split8(p0, p1, hi, lo);
    smA[0][(w * 2 + 0) * 128 + lane] = hi;
    smA[0][(w * 2 + 0) * 128 + 64 + lane] = lo;
    split8(p2, p3, hi, lo);
    smA[0][(w * 2 + 1) * 128 + lane] = hi;
    smA[0][(w * 2 + 1) * 128 + 64 + lane] = lo;
  }
  // ---- prefetch B (kt=0, s=0) ----
  v8s bc[8], bn[8];
  #pragma unroll
  for (int j = 0; j < 4; ++j) {
    bc[j * 2]     = *(const v8s*)&wbB[((j * 2 + 0) * 2 + 0) * 64];
    bc[j * 2 + 1] = *(const v8s*)&wbB[((j * 2 + 0) * 2 + 1) * 64];
  }
  __syncthreads();

  for (int kt = 0; kt < 32; ++kt) {
    const int cur = kt & 1;
    float4 q0, q1, q2, q3;
    if (kt < 31) {                      // issue next A-slice loads early
      const float* an = arow + (kt + 1) * 32;
      q0 = *(const float4*)(an);
      q1 = *(const float4*)(an + 4);
      q2 = *(const float4*)(an + 16);
      q3 = *(const float4*)(an + 20);
    }
    #pragma unroll
    for (int s = 0; s < 2; ++s) {
      const int nkt = s ? kt + 1 : kt, ns = s ^ 1;
      if (nkt < 32) {                   // prefetch next B half-slice
        #pragma unroll
        for (int j = 0; j < 4; ++j) {
          bn[j * 2]     = *(const v8s*)&wbB[(size_t)nkt * 1024 + ((j * 2 + ns) * 2 + 0) * 64];
          bn[j * 2 + 1] = *(const v8s*)&wbB[(size_t)nkt * 1024 + ((j * 2 + ns) * 2 + 1) * 64];
        }
      }
      v8s ah[2], al[2];
      #pragma unroll
      for (int i = 0; i < 2; ++i) {
        int base = ((wm * 2 + i) * 2 + s) * 128 + lane;
        ah[i] = *(const v8s*)&smA[cur][base];
        al[i] = *(const v8s*)&smA[cur][base + 64];
      }
      #pragma unroll
      for (int j = 0; j < 4; ++j) {
        v8s bh = bc[j * 2], bl = bc[j * 2 + 1];
        #pragma unroll
        for (int i = 0; i < 2; ++i) {
          acc[i][j] = __builtin_amdgcn_mfma_f32_32x32x16_bf16(ah[i], bh, acc[i][j], 0, 0, 0);
          acc[i][j] = __builtin_amdgcn_mfma_f32_32x32x16_bf16(ah[i], bl, acc[i][j], 0, 0, 0);
          acc[i][j] = __builtin_amdgcn_mfma_f32_32x32x16_bf16(al[i], bh, acc[i][j], 0, 0, 0);
        }
      }
      #pragma unroll
      for (int e = 0; e < 8; ++e) bc[e] = bn[e];
    }
    if (kt < 31) {                      // split + store kt+1 into other buf
      uint4 hi, lo;
      split8(q0, q1, hi, lo);
      smA[cur ^ 1][(w * 2 + 0) * 128 + lane] = hi;
      smA[cur ^ 1][(w * 2 + 0) * 128 + 64 + lane] = lo;
      split8(q2, q3, hi, lo);
      smA[cur ^ 1][(w * 2 + 1) * 128 + lane] = hi;
      smA[cur ^ 1][(w * 2 + 1) * 128 + 64 + lane] = lo;
    }
    __syncthreads();
  }

  // column-max epilogue: 32x32 C/D layout, col = lane&31
  #pragma unroll
  for (int j = 0; j < 4; ++j) {
    float m = -INFINITY;
    #pragma unroll
    for (int i = 0; i < 2; ++i)
      #pragma unroll
      for (int e = 0; e < 16; ++e) m = fmaxf(m, acc[i][j][e]);
    m = fmaxf(m, __shfl_xor(m, 32));
    if (lane < 32) {
      int col = strip * 256 + wn * 128 + j * 32 + lane;
      unsigned u = __float_as_uint(m);
      unsigned enc = (m >= 0.f) ? (u | 0x80000000u) : ~u;  // order-preserving encode
      atomicMax(&ymax[batch * CH + col], enc);
    }
  }
}

// ---------------- m1 = xsum@W^T/2048 + b  AND  amax = decode(ymax) + b ----------------
__global__ __launch_bounds__(256) void poolmix_kernel(const float* __restrict__ xsum,
                                                      const unsigned* __restrict__ ymax,
                                                      const float* __restrict__ W,
                                                      const float* __restrict__ bias,
                                                      float* __restrict__ m1,
                                                      float* __restrict__ amax) {
  int t = threadIdx.x;
  int id = blockIdx.x * 256 + t;                   // decode lane: 0..32767
  unsigned u = ymax[id];
  float f = (u & 0x80000000u) ? __uint_as_float(u & 0x7FFFFFFFu) : __uint_as_float(~u);
  amax[id] = f + bias[id & (CH - 1)];

  int d = blockIdx.x * 8 + (t >> 5);
  int b = t & 31;
  const float4* Ir = (const float4*)(xsum + b * CH);
  const float4* Mr = (const float4*)(W + (size_t)d * CH);
  float acc = 0.f;
  #pragma unroll 4
  for (int c = 0; c < CH / 4; ++c) {
    float4 a = Ir[c], m = Mr[c];
    acc += a.x * m.x + a.y * m.y + a.z * m.z + a.w * m.w;
  }
  m1[b * CH + d] = acc * (1.f / 2048.f) + bias[d];
}

// ---------------- t1 = m1@Wm^T + bm ; t2 = amax@Wa^T + ba (fused, z-split) ----------
__global__ __launch_bounds__(256) void lin2_kernel(const float* __restrict__ m1,
                                                   const float* __restrict__ amax,
                                                   const float* __restrict__ Wm,
                                                   const float* __restrict__ bm,
                                                   const float* __restrict__ Wa,
                                                   const float* __restrict__ ba,
                                                   float* __restrict__ t1,
                                                   float* __restrict__ t2) {
  int t = threadIdx.x;
  int which = blockIdx.x >> 7, bk = blockIdx.x & 127;
  const float* I = which ? amax : m1;
  const float* M = which ? Wa : Wm;
  const float* bb = which ? ba : bm;
  float* O = which ? t2 : t1;
  int d = bk * 8 + (t >> 5);
  int b = t & 31;
  const float4* Ir = (const float4*)(I + b * CH);
  const float4* Mr = (const float4*)(M + (size_t)d * CH);
  float acc = 0.f;
  #pragma unroll 4
  for (int c = 0; c < CH / 4; ++c) {
    float4 a = Ir[c], m = Mr[c];
    acc += a.x * m.x + a.y * m.y + a.z * m.z + a.w * m.w;
  }
  O[b * CH + d] = acc + bb[d];
}

// ---------------- GroupNorm both branches, emit p = gn1(t1)+gn2(t2) ----------------
__global__ __launch_bounds__(1024) void gnp_kernel(const float* __restrict__ t1,
                                                   const float* __restrict__ t2,
                                                   const float* __restrict__ g1w, const float* __restrict__ g1b,
                                                   const float* __restrict__ g2w, const float* __restrict__ g2b,
                                                   float* __restrict__ p) {
  int b = blockIdx.x, c = threadIdx.x;
  float v1 = t1[b * CH + c], v2 = t2[b * CH + c];
  float s1 = v1, s2 = v2;
  #pragma unroll
  for (int off = 16; off; off >>= 1) { s1 += __shfl_xor(s1, off); s2 += __shfl_xor(s2, off); }
  float d1 = v1 - s1 * (1.f / 32.f), d2 = v2 - s2 * (1.f / 32.f);
  float q1 = d1 * d1, q2 = d2 * d2;
  #pragma unroll
  for (int off = 16; off; off >>= 1) { q1 += __shfl_xor(q1, off); q2 += __shfl_xor(q2, off); }
  float o1 = d1 * rsqrtf(q1 * (1.f / 32.f) + 1e-5f) * g1w[c] + g1b[c];
  float o2 = d2 * rsqrtf(q2 * (1.f / 32.f) + 1e-5f) * g2w[c] + g2b[c];
  p[b * CH + c] = o1 + o2;
}

// ---------------- O[b][e] += sum_{c in chunk} S[b][c] * M[c][e] ----------------
__global__ __launch_bounds__(256) void colmm_kernel(const float* __restrict__ S,
                                                    const float* __restrict__ M,
                                                    float* __restrict__ O) {
  __shared__ float Sl[128][32];
  int t = threadIdx.x;
  int e0 = (blockIdx.x & 3) * 256, c0 = (blockIdx.x >> 2) * 128;
  for (int i = t; i < 4096; i += 256) {
    int c = i >> 5, b = i & 31;
    Sl[c][b] = S[b * CH + c0 + c];
  }
  __syncthreads();
  int e = e0 + t;
  float acc[32];
  #pragma unroll
  for (int b = 0; b < 32; ++b) acc[b] = 0.f;
  for (int c = 0; c < 128; ++c) {
    float wv = M[(size_t)(c0 + c) * CH + e];
    #pragma unroll
    for (int b = 0; b < 32; ++b) acc[b] += Sl[c][b] * wv;
  }
  #pragma unroll
  for (int b = 0; b < 32; ++b) atomicAdd(&O[b * CH + e], acc[b]);
}

// ---------------- logits s[b][l] = x[b][l][:] . v[b][:] ----------------
__global__ __launch_bounds__(256) void logits_kernel(const float* __restrict__ x,
                                                     const float* __restrict__ v,
                                                     float* __restrict__ s) {
  __shared__ float4 vl[256];
  int b = blockIdx.y, chunk = blockIdx.x, t = threadIdx.x;
  vl[t] = ((const float4*)(v + b * CH))[t];
  __syncthreads();
  int wv = t >> 6, lane = t & 63;
  for (int it = 0; it < 8; ++it) {
    int l = chunk * 32 + it * 4 + wv;
    const float4* xr = (const float4*)(x + ((size_t)b * L_SEQ + l) * CH);
    float acc = 0.f;
    #pragma unroll
    for (int rep = 0; rep < 4; ++rep) {
      float4 a = xr[rep * 64 + lane];
      float4 c = vl[rep * 64 + lane];
      acc += a.x * c.x + a.y * c.y + a.z * c.z + a.w * c.w;
    }
    #pragma unroll
    for (int off = 32; off; off >>= 1) acc += __shfl_xor(acc, off);
    if (lane == 0) s[b * L_SEQ + l] = acc;
  }
}

// ---------------- top-20 (desc, ties -> lower index), register-resident ------------
__global__ __launch_bounds__(256) void topk_kernel(const float* __restrict__ s,
                                                   int* __restrict__ idx_out) {
  int b = blockIdx.x, t = threadIdx.x;
  int lane = t & 63, w = t >> 6;
  __shared__ float lv[4];
  __shared__ int   li[4];
  float v[8];
  #pragma unroll
  for (int j = 0; j < 8; ++j) v[j] = s[b * L_SEQ + j * 256 + t];
  for (int k = 0; k < KSEL; ++k) {
    float bv = -INFINITY; int bi = 1 << 30;
    #pragma unroll
    for (int j = 0; j < 8; ++j) {
      int gi = j * 256 + t;
      if (v[j] > bv || (v[j] == bv && gi < bi)) { bv = v[j]; bi = gi; }
    }
    #pragma unroll
    for (int off = 32; off; off >>= 1) {
      float ov = __shfl_xor(bv, off); int oi = __shfl_xor(bi, off);
      if (ov > bv || (ov == bv && oi < bi)) { bv = ov; bi = oi; }
    }
    if (lane == 0) { lv[w] = bv; li[w] = bi; }
    __syncthreads();
    float fv = lv[0]; int fi = li[0];
    #pragma unroll
    for (int w2 = 1; w2 < 4; ++w2) {
      float ov = lv[w2]; int oi = li[w2];
      if (ov > fv || (ov == fv && oi < fi)) { fv = ov; fi = oi; }
    }
    if (t == 0) idx_out[b * KSEL + k] = fi;
    if ((fi & 255) == t) v[fi >> 8] = -INFINITY;
    __syncthreads();
  }
}

// ---------------- selected-row GEMM #1 with fused gather: Y = x[idx]@W^T + b -------
__global__ __launch_bounds__(256) void selgemm_idx_kernel(const float* __restrict__ X,
                                                          const int* __restrict__ idx,
                                                          const float* __restrict__ B,
                                                          const float* __restrict__ bias,
                                                          float* __restrict__ C) {
  __shared__ float As[64][17];
  __shared__ float Bs[64][17];
  __shared__ int rmap[64];
  int t = threadIdx.x;
  int tx = t & 15, ty = t >> 4;
  int n0 = blockIdx.x * 64, m0 = blockIdx.y * 64;
  if (t < 64) {
    int rr = m0 + t;
    rmap[t] = (rr / KSEL) * L_SEQ + idx[rr];
  }
  __syncthreads();
  float acc[4][4];
  #pragma unroll
  for (int i = 0; i < 4; ++i)
    #pragma unroll
    for (int j = 0; j < 4; ++j) acc[i][j] = 0.f;
  for (int k0 = 0; k0 < CH; k0 += 16) {
    #pragma unroll
    for (int j = 0; j < 4; ++j) {
      int e = t * 4 + j;
      int row = e >> 4, kk = e & 15;
      As[row][kk] = X[(size_t)rmap[row] * CH + k0 + kk];
      Bs[row][kk] = B[(size_t)(n0 + row) * CH + k0 + kk];
    }
    __syncthreads();
    #pragma unroll
    for (int kk = 0; kk < 16; ++kk) {
      float a[4], bb[4];
      #pragma unroll
      for (int i = 0; i < 4; ++i) a[i] = As[ty * 4 + i][kk];
      #pragma unroll
      for (int j = 0; j < 4; ++j) bb[j] = Bs[tx * 4 + j][kk];
      #pragma unroll
      for (int i = 0; i < 4; ++i)
        #pragma unroll
        for (int j = 0; j < 4; ++j) acc[i][j] += a[i] * bb[j];
    }
    __syncthreads();
  }
  #pragma unroll
  for (int i = 0; i < 4; ++i)
    #pragma unroll
    for (int j = 0; j < 4; ++j)
      C[(size_t)(m0 + ty * 4 + i) * CH + n0 + tx * 4 + j] = acc[i][j] + bias[n0 + tx * 4 + j];
}

// ---------------- selected-row GEMM #2: C = A@B^T + bias ----------------
__global__ __launch_bounds__(256) void selgemm_kernel(const float* __restrict__ A,
                                                      const float* __restrict__ B,
                                                      const float* __restrict__ bias,
                                                      float* __restrict__ C) {
  __shared__ float As[64][17];
  __shared__ float Bs[64][17];
  int t = threadIdx.x;
  int tx = t & 15, ty = t >> 4;
  int n0 = blockIdx.x * 64, m0 = blockIdx.y * 64;
  float acc[4][4];
  #pragma unroll
  for (int i = 0; i < 4; ++i)
    #pragma unroll
    for (int j = 0; j < 4; ++j) acc[i][j] = 0.f;
  for (int k0 = 0; k0 < CH; k0 += 16) {
    #pragma unroll
    for (int j = 0; j < 4; ++j) {
      int e = t * 4 + j;
      int row = e >> 4, kk = e & 15;
      As[row][kk] = A[(size_t)(m0 + row) * CH + k0 + kk];
      Bs[row][kk] = B[(size_t)(n0 + row) * CH + k0 + kk];
    }
    __syncthreads();
    #pragma unroll
    for (int kk = 0; kk < 16; ++kk) {
      float a[4], bb[4];
      #pragma unroll
      for (int i = 0; i < 4; ++i) a[i] = As[ty * 4 + i][kk];
      #pragma unroll
      for (int j = 0; j < 4; ++j) bb[j] = Bs[tx * 4 + j][kk];
      #pragma unroll
      for (int i = 0; i < 4; ++i)
        #pragma unroll
        for (int j = 0; j < 4; ++j) acc[i][j] += a[i] * bb[j];
    }
    __syncthreads();
  }
  #pragma unroll
  for (int i = 0; i < 4; ++i)
    #pragma unroll
    for (int j = 0; j < 4; ++j)
      C[(size_t)(m0 + ty * 4 + i) * CH + n0 + tx * 4 + j] = acc[i][j] + bias[n0 + tx * 4 + j];
}

extern "C" void kernel_launch(void* const* d_in, const int* in_sizes, int n_in,
                              void* d_out, int out_size, void* d_ws, size_t ws_size,
                              hipStream_t stream) {
  const float* x   = (const float*)d_in[0];
  const float* W   = (const float*)d_in[1];
  const float* b   = (const float*)d_in[2];
  const float* W1  = (const float*)d_in[3];
  const float* b1  = (const float*)d_in[4];
  const float* Wm  = (const float*)d_in[5];
  const float* bm  = (const float*)d_in[6];
  const float* Wa  = (const float*)d_in[7];
  const float* ba  = (const float*)d_in[8];
  const float* g1w = (const float*)d_in[9];
  const float* g1b = (const float*)d_in[10];
  const float* g2w = (const float*)d_in[11];
  const float* g2b = (const float*)d_in[12];

  float* wsf = (float*)d_ws;
  float*    xsum = wsf + WS_XSUM;
  unsigned* ymax = (unsigned*)(wsf + WS_YMAX);
  float*    m1   = wsf + WS_M1;
  float*    amax = wsf + WS_AMAX;
  float*    t1   = wsf + WS_T1;
  float*    t2   = wsf + WS_T2;
  float*    p    = wsf + WS_P;
  float*    u    = wsf + WS_U;
  float*    vvec = wsf + WS_V;
  float*    sbuf = wsf + WS_S;
  int*      tidx = (int*)(wsf + WS_TOPK);
  float*    Ysel = wsf + WS_YSEL;
  uint4*    wpak = (uint4*)(wsf + WS_WP);

  packw_kernel<<<dim3(32, 8), 256, 0, stream>>>(W, wpak, wsf);
  mean_kernel<<<dim3(32, 32), 256, 0, stream>>>(x, xsum);
  gemm_max4<<<2048, 256, 0, stream>>>(x, wpak, ymax);

  poolmix_kernel<<<128, 256, 0, stream>>>(xsum, ymax, W, b, m1, amax);
  lin2_kernel<<<256, 256, 0, stream>>>(m1, amax, Wm, bm, Wa, ba, t1, t2);
  gnp_kernel<<<32, 1024, 0, stream>>>(t1, t2, g1w, g1b, g2w, g2b, p);
  colmm_kernel<<<32, 256, 0, stream>>>(p, W1, u);     // u = W1^T p
  colmm_kernel<<<32, 256, 0, stream>>>(u, W, vvec);   // v = W^T u
  logits_kernel<<<dim3(64, 32), 256, 0, stream>>>(x, vvec, sbuf);
  topk_kernel<<<32, 256, 0, stream>>>(sbuf, tidx);
  selgemm_idx_kernel<<<dim3(16, 10), 256, 0, stream>>>(x, tidx, W, b, Ysel);
  selgemm_kernel<<<dim3(16, 10), 256, 0, stream>>>(Ysel, W1, b1, (float*)d_out);
}

// Round 5
// 1045.476 us; speedup vs baseline: 1.1780x; 1.0500x over previous
//
#include <hip/hip_runtime.h>

#define L_SEQ 2048
#define CH    1024
#define NB    32
#define KSEL  20

typedef short v8s  __attribute__((ext_vector_type(8)));
typedef float v16f __attribute__((ext_vector_type(16)));

// ---------------- workspace layout (float offsets) ----------------
#define WS_XSUM   0          // [32*1024] f32   column sums of x
#define WS_YMAX   32768      // [32*1024] u32   encoded col-max of y
#define WS_M1     65536      // [32*1024] f32   mean-pool @ W^T + b
#define WS_AMAX   98304      // [32*1024] f32   decoded max-pool + b
#define WS_T1     131072     // [32*1024] f32
#define WS_T2     163840     // [32*1024] f32
#define WS_P      196608     // [32*1024] f32   gn1(t1)+gn2(t2)
#define WS_V      294912     // [32*1024] f32   v = Wc^T p
#define WS_S      327680     // [32*2048] f32   logit sums
#define WS_TOPK   393216     // [640] int
#define WS_BC     394240     // [1024] f32      bc = W1 b + b1
#define WS_WC     395264     // [1024*1024] f32 Wc = W1 W (row-major [d][c])
#define WS_WPAK   1443840    // 4 MB: packed W  (frag-major split-bf16)
#define WS_WTPAK  2492416    // 4 MB: packed W^T; REUSED later for packed Wc

// ---------------- fp32 -> (hi,lo) bf16 split, 8 elems -> two uint4 ----------------
__device__ __forceinline__ void split8(float4 qa, float4 qb, uint4& hi, uint4& lo) {
  float f[8] = {qa.x, qa.y, qa.z, qa.w, qb.x, qb.y, qb.z, qb.w};
  unsigned h[8], l[8];
  #pragma unroll
  for (int e = 0; e < 8; ++e) {
    unsigned u  = __float_as_uint(f[e]);
    unsigned hu = u & 0xFFFF0000u;                 // truncated hi bf16
    float lf    = f[e] - __uint_as_float(hu);      // residual
    h[e] = u >> 16;
    l[e] = __float_as_uint(lf) >> 16;              // truncated lo bf16
  }
  hi.x = h[0] | (h[1] << 16); hi.y = h[2] | (h[3] << 16);
  hi.z = h[4] | (h[5] << 16); hi.w = h[6] | (h[7] << 16);
  lo.x = l[0] | (l[1] << 16); lo.y = l[2] | (l[3] << 16);
  lo.z = l[4] | (l[5] << 16); lo.w = l[6] | (l[7] << 16);
}

// ---------------- pack row-major M -> frag-major split-bf16 ----------------
// chunk (Rw, kt) = 1024 uint4; slot = ((r>>5)*2 + (p>>1))*128 + (p&1)*32 + (r&31)
__global__ __launch_bounds__(256) void packw_kernel(const float* __restrict__ W,
                                                    uint4* __restrict__ wp,
                                                    float* __restrict__ zws) {
  int t = threadIdx.x, kt = blockIdx.x, Rw = blockIdx.y;
  if (zws) {     // fold zero-init: xsum+ymax (65536 f) and v (32768 f)
    int flat = (Rw * 32 + kt) * 256 + t;
    zws[WS_XSUM + flat] = 0.f;
    if (flat < 32768) zws[WS_V + flat] = 0.f;
  }
  const float* wb = W + (size_t)Rw * 128 * CH;
  uint4* out = wp + ((size_t)Rw * 32 + kt) * 1024;
  #pragma unroll
  for (int pass = 0; pass < 2; ++pass) {
    int idx = pass * 256 + t;
    int r = idx >> 2, p = idx & 3;
    const float* ap = wb + (size_t)r * CH + kt * 32 + p * 8;
    float4 f0 = *(const float4*)ap;
    float4 f1 = *(const float4*)(ap + 4);
    uint4 hi, lo;
    split8(f0, f1, hi, lo);
    int slot = ((r >> 5) * 2 + (p >> 1)) * 128 + (p & 1) * 32 + (r & 31);
    out[slot] = hi;
    out[slot + 64] = lo;
  }
}

// ---------------- pack W^T (LDS transpose) -> frag-major split-bf16 -------------
__global__ __launch_bounds__(256) void packwt_kernel(const float* __restrict__ W,
                                                     uint4* __restrict__ wtp) {
  __shared__ float Wl[32][129];
  int t = threadIdx.x, kt = blockIdx.x, cc = blockIdx.y;
  #pragma unroll
  for (int it = 0; it < 16; ++it) {
    int idx = it * 256 + t;
    int el = idx >> 7, cl = idx & 127;
    Wl[el][cl] = W[(size_t)(kt * 32 + el) * CH + cc * 128 + cl];
  }
  __syncthreads();
  uint4* out = wtp + ((size_t)cc * 32 + kt) * 1024;
  #pragma unroll
  for (int pass = 0; pass < 2; ++pass) {
    int sid = pass * 256 + t;
    int r = sid >> 2, p = sid & 3;
    float f[8];
    #pragma unroll
    for (int q = 0; q < 8; ++q) f[q] = Wl[p * 8 + q][r];
    float4 f0 = {f[0], f[1], f[2], f[3]}, f1 = {f[4], f[5], f[6], f[7]};
    uint4 hi, lo;
    split8(f0, f1, hi, lo);
    int slot = ((r >> 5) * 2 + (p >> 1)) * 128 + (p & 1) * 32 + (r & 31);
    out[slot] = hi;
    out[slot + 64] = lo;
  }
}

// ---------------- column means of x (atomic partial sums) ----------------
__global__ __launch_bounds__(256) void mean_kernel(const float* __restrict__ x,
                                                   float* __restrict__ xsum) {
  int b = blockIdx.y, chunk = blockIdx.x, t = threadIdx.x;
  const float4* bp = (const float4*)(x + ((size_t)b * L_SEQ + (size_t)chunk * 64) * CH);
  float sx = 0.f, sy = 0.f, sz = 0.f, sw = 0.f;
  #pragma unroll 4
  for (int l = 0; l < 64; ++l) {
    float4 a = bp[l * 256 + t];
    sx += a.x; sy += a.y; sz += a.z; sw += a.w;
  }
  float* dst = xsum + b * CH + t * 4;
  atomicAdd(dst + 0, sx); atomicAdd(dst + 1, sy);
  atomicAdd(dst + 2, sz); atomicAdd(dst + 3, sw);
}

// ---------------- shared GEMM K-loop core ----------------
// Block 128m x 256n, 4 waves, wave w = wn: tile 128m x 64n (i:4 m-tiles, j:2 n-tiles).
// A: f32 -> split -> LDS dbuf (conflict-free). B: packed frag direct from global (L2).
// B traffic/wave/kt = 8 KB -> ~21 B/cyc/CU, under the measured ~42 B/cyc L2 cap.
template<bool FOURTH>
__device__ __forceinline__ void gemm_core(const float* __restrict__ arow,
                                          const uint4* __restrict__ wbB,
                                          const int cgbase,
                                          uint4 (*__restrict__ smA)[1024],
                                          const int w, const int lane,
                                          v16f acc[4][2]) {
  {  // stage kt=0 into buf 0
    float4 p0 = *(const float4*)(arow);
    float4 p1 = *(const float4*)(arow + 4);
    float4 p2 = *(const float4*)(arow + 16);
    float4 p3 = *(const float4*)(arow + 20);
    uint4 hi, lo;
    split8(p0, p1, hi, lo);
    smA[0][(w * 2 + 0) * 128 + lane] = hi;
    smA[0][(w * 2 + 0) * 128 + 64 + lane] = lo;
    split8(p2, p3, hi, lo);
    smA[0][(w * 2 + 1) * 128 + lane] = hi;
    smA[0][(w * 2 + 1) * 128 + 64 + lane] = lo;
  }
  v8s bc[4], bn[4];
  #pragma unroll
  for (int j = 0; j < 2; ++j) {
    bc[j * 2]     = *(const v8s*)&wbB[((cgbase + j) * 2 + 0) * 128];
    bc[j * 2 + 1] = *(const v8s*)&wbB[((cgbase + j) * 2 + 0) * 128 + 64];
  }
  __syncthreads();

  for (int kt = 0; kt < 32; ++kt) {
    const int cur = kt & 1;
    float4 q0, q1, q2, q3;
    if (kt < 31) {                      // issue next A-slice loads early
      const float* an = arow + (kt + 1) * 32;
      q0 = *(const float4*)(an);
      q1 = *(const float4*)(an + 4);
      q2 = *(const float4*)(an + 16);
      q3 = *(const float4*)(an + 20);
    }
    #pragma unroll
    for (int s = 0; s < 2; ++s) {
      const int nkt = s ? kt + 1 : kt, ns = s ^ 1;
      if (nkt < 32) {                   // prefetch next B half-slice (4 loads)
        #pragma unroll
        for (int j = 0; j < 2; ++j) {
          bn[j * 2]     = *(const v8s*)&wbB[(size_t)nkt * 1024 + ((cgbase + j) * 2 + ns) * 128];
          bn[j * 2 + 1] = *(const v8s*)&wbB[(size_t)nkt * 1024 + ((cgbase + j) * 2 + ns) * 128 + 64];
        }
      }
      v8s ah[4], al[4];
      #pragma unroll
      for (int i = 0; i < 4; ++i) {
        int base = (i * 2 + s) * 128 + lane;
        ah[i] = *(const v8s*)&smA[cur][base];
        al[i] = *(const v8s*)&smA[cur][base + 64];
      }
      #pragma unroll
      for (int j = 0; j < 2; ++j) {
        v8s bh = bc[j * 2], bl = bc[j * 2 + 1];
        #pragma unroll
        for (int i = 0; i < 4; ++i) {
          acc[i][j] = __builtin_amdgcn_mfma_f32_32x32x16_bf16(ah[i], bh, acc[i][j], 0, 0, 0);
          acc[i][j] = __builtin_amdgcn_mfma_f32_32x32x16_bf16(ah[i], bl, acc[i][j], 0, 0, 0);
          acc[i][j] = __builtin_amdgcn_mfma_f32_32x32x16_bf16(al[i], bh, acc[i][j], 0, 0, 0);
          if (FOURTH)
            acc[i][j] = __builtin_amdgcn_mfma_f32_32x32x16_bf16(al[i], bl, acc[i][j], 0, 0, 0);
        }
      }
      #pragma unroll
      for (int e = 0; e < 4; ++e) bc[e] = bn[e];
    }
    if (kt < 31) {                      // split + store kt+1 into other buf
      uint4 hi, lo;
      split8(q0, q1, hi, lo);
      smA[cur ^ 1][(w * 2 + 0) * 128 + lane] = hi;
      smA[cur ^ 1][(w * 2 + 0) * 128 + 64 + lane] = lo;
      split8(q2, q3, hi, lo);
      smA[cur ^ 1][(w * 2 + 1) * 128 + lane] = hi;
      smA[cur ^ 1][(w * 2 + 1) * 128 + 64 + lane] = lo;
    }
    __syncthreads();
  }
}

// ---------------- big GEMM + column max (3-term split-bf16) ----------------
__global__ __launch_bounds__(256, 2) void gemm_max5(const float* __restrict__ X,
                                                    const uint4* __restrict__ wp,
                                                    unsigned* __restrict__ ymax) {
  __shared__ uint4 smA[2][1024];        // 32 KB dbuf -> 2 blocks/CU
  const int t = threadIdx.x, lane = t & 63, w = t >> 6;
  const int blk = blockIdx.x;
  const int strip = blk & 3, mt = blk >> 2;
  const int batch = mt >> 4;
  const float* arow = X + (size_t)(mt * 128 + w * 32 + (lane & 31)) * CH + (lane >> 5) * 8;
  v16f acc[4][2];
  #pragma unroll
  for (int i = 0; i < 4; ++i)
    #pragma unroll
    for (int j = 0; j < 2; ++j)
      #pragma unroll
      for (int e = 0; e < 16; ++e) acc[i][j][e] = 0.f;
  const uint4* wbB = wp + (size_t)(strip * 2 + (w >> 1)) * 32768 + lane;
  gemm_core<false>(arow, wbB, (w & 1) * 2, smA, w, lane, acc);

  // column-max epilogue: 32x32 C/D layout, col = lane&31
  #pragma unroll
  for (int j = 0; j < 2; ++j) {
    float m = -INFINITY;
    #pragma unroll
    for (int i = 0; i < 4; ++i)
      #pragma unroll
      for (int e = 0; e < 16; ++e) m = fmaxf(m, acc[i][j][e]);
    m = fmaxf(m, __shfl_xor(m, 32));
    if (lane < 32) {
      int col = strip * 256 + w * 64 + j * 32 + lane;
      unsigned u = __float_as_uint(m);
      unsigned enc = (m >= 0.f) ? (u | 0x80000000u) : ~u;  // order-preserving encode
      atomicMax(&ymax[batch * CH + col], enc);
    }
  }
}

// ---------------- Wc = W1 @ W (4-term split-bf16, ~fp32-exact) ----------------
__global__ __launch_bounds__(256, 2) void wc_gemm(const float* __restrict__ W1,
                                                  const uint4* __restrict__ wtp,
                                                  float* __restrict__ Wc) {
  __shared__ uint4 smA[2][1024];
  const int t = threadIdx.x, lane = t & 63, w = t >> 6;
  const int blk = blockIdx.x;
  const int strip = blk & 3, mt = blk >> 2;      // mt 0..7
  const float* arow = W1 + (size_t)(mt * 128 + w * 32 + (lane & 31)) * CH + (lane >> 5) * 8;
  v16f acc[4][2];
  #pragma unroll
  for (int i = 0; i < 4; ++i)
    #pragma unroll
    for (int j = 0; j < 2; ++j)
      #pragma unroll
      for (int e = 0; e < 16; ++e) acc[i][j][e] = 0.f;
  const uint4* wbB = wtp + (size_t)(strip * 2 + (w >> 1)) * 32768 + lane;
  gemm_core<true>(arow, wbB, (w & 1) * 2, smA, w, lane, acc);

  #pragma unroll
  for (int i = 0; i < 4; ++i)
    #pragma unroll
    for (int j = 0; j < 2; ++j)
      #pragma unroll
      for (int r = 0; r < 16; ++r) {
        int row = (r & 3) + 8 * (r >> 2) + 4 * (lane >> 5);
        int grow = mt * 128 + i * 32 + row;
        int gcol = strip * 256 + w * 64 + j * 32 + (lane & 31);
        Wc[(size_t)grow * CH + gcol] = acc[i][j][r];
      }
}

// ---------------- out = x[sel] @ Wc^T + bc (4-term) ----------------
__global__ __launch_bounds__(256, 2) void out_gemm(const float* __restrict__ X,
                                                   const int* __restrict__ idx,
                                                   const uint4* __restrict__ wcp,
                                                   const float* __restrict__ bc,
                                                   float* __restrict__ C) {
  __shared__ uint4 smA[2][1024];
  const int t = threadIdx.x, lane = t & 63, w = t >> 6;
  const int blk = blockIdx.x;
  const int strip = blk & 3, mt = blk >> 2;      // mt 0..4 (640 rows exactly)
  const int rr = mt * 128 + w * 32 + (lane & 31);
  const int grow_a = (rr / KSEL) * L_SEQ + idx[rr];
  const float* arow = X + (size_t)grow_a * CH + (lane >> 5) * 8;
  v16f acc[4][2];
  #pragma unroll
  for (int i = 0; i < 4; ++i)
    #pragma unroll
    for (int j = 0; j < 2; ++j)
      #pragma unroll
      for (int e = 0; e < 16; ++e) acc[i][j][e] = 0.f;
  const uint4* wbB = wcp + (size_t)(strip * 2 + (w >> 1)) * 32768 + lane;
  gemm_core<true>(arow, wbB, (w & 1) * 2, smA, w, lane, acc);

  #pragma unroll
  for (int i = 0; i < 4; ++i)
    #pragma unroll
    for (int j = 0; j < 2; ++j)
      #pragma unroll
      for (int r = 0; r < 16; ++r) {
        int row = (r & 3) + 8 * (r >> 2) + 4 * (lane >> 5);
        int grow = mt * 128 + i * 32 + row;
        int gcol = strip * 256 + w * 64 + j * 32 + (lane & 31);
        C[(size_t)grow * CH + gcol] = acc[i][j][r] + bc[gcol];
      }
}

// ---------------- bc = W1 @ b + b1 ----------------
__global__ __launch_bounds__(256) void bc_kernel(const float* __restrict__ W1,
                                                 const float* __restrict__ b,
                                                 const float* __restrict__ b1,
                                                 float* __restrict__ bc) {
  int t = threadIdx.x;
  int d = blockIdx.x * 8 + (t >> 5);
  int lane = t & 31;
  const float4* wr = (const float4*)(W1 + (size_t)d * CH);
  const float4* br = (const float4*)b;
  float acc = 0.f;
  #pragma unroll
  for (int c = lane; c < 256; c += 32) {
    float4 a = wr[c], m = br[c];
    acc += a.x * m.x + a.y * m.y + a.z * m.z + a.w * m.w;
  }
  #pragma unroll
  for (int off = 16; off; off >>= 1) acc += __shfl_xor(acc, off);
  if (lane == 0) bc[d] = acc + b1[d];
}

// ---------------- m1 = xsum@W^T/2048 + b  AND  amax = decode(ymax) + b -------------
__global__ __launch_bounds__(256) void poolmix_kernel(const float* __restrict__ xsum,
                                                      const unsigned* __restrict__ ymax,
                                                      const float* __restrict__ W,
                                                      const float* __restrict__ bias,
                                                      float* __restrict__ m1,
                                                      float* __restrict__ amax) {
  int t = threadIdx.x;
  int id = blockIdx.x * 256 + t;
  unsigned u = ymax[id];
  float f = (u & 0x80000000u) ? __uint_as_float(u & 0x7FFFFFFFu) : __uint_as_float(~u);
  amax[id] = f + bias[id & (CH - 1)];

  int d = blockIdx.x * 8 + (t >> 5);
  int b = t & 31;
  const float4* Ir = (const float4*)(xsum + b * CH);
  const float4* Mr = (const float4*)(W + (size_t)d * CH);
  float acc = 0.f;
  #pragma unroll 4
  for (int c = 0; c < CH / 4; ++c) {
    float4 a = Ir[c], m = Mr[c];
    acc += a.x * m.x + a.y * m.y + a.z * m.z + a.w * m.w;
  }
  m1[b * CH + d] = acc * (1.f / 2048.f) + bias[d];
}

// ---------------- t1 = m1@Wm^T + bm ; t2 = amax@Wa^T + ba ----------------
__global__ __launch_bounds__(256) void lin2_kernel(const float* __restrict__ m1,
                                                   const float* __restrict__ amax,
                                                   const float* __restrict__ Wm,
                                                   const float* __restrict__ bm,
                                                   const float* __restrict__ Wa,
                                                   const float* __restrict__ ba,
                                                   float* __restrict__ t1,
                                                   float* __restrict__ t2) {
  int t = threadIdx.x;
  int which = blockIdx.x >> 7, bk = blockIdx.x & 127;
  const float* I = which ? amax : m1;
  const float* M = which ? Wa : Wm;
  const float* bb = which ? ba : bm;
  float* O = which ? t2 : t1;
  int d = bk * 8 + (t >> 5);
  int b = t & 31;
  const float4* Ir = (const float4*)(I + b * CH);
  const float4* Mr = (const float4*)(M + (size_t)d * CH);
  float acc = 0.f;
  #pragma unroll 4
  for (int c = 0; c < CH / 4; ++c) {
    float4 a = Ir[c], m = Mr[c];
    acc += a.x * m.x + a.y * m.y + a.z * m.z + a.w * m.w;
  }
  O[b * CH + d] = acc + bb[d];
}

// ---------------- GroupNorm both branches, emit p = gn1(t1)+gn2(t2) ----------------
__global__ __launch_bounds__(1024) void gnp_kernel(const float* __restrict__ t1,
                                                   const float* __restrict__ t2,
                                                   const float* __restrict__ g1w, const float* __restrict__ g1b,
                                                   const float* __restrict__ g2w, const float* __restrict__ g2b,
                                                   float* __restrict__ p) {
  int b = blockIdx.x, c = threadIdx.x;
  float v1 = t1[b * CH + c], v2 = t2[b * CH + c];
  float s1 = v1, s2 = v2;
  #pragma unroll
  for (int off = 16; off; off >>= 1) { s1 += __shfl_xor(s1, off); s2 += __shfl_xor(s2, off); }
  float d1 = v1 - s1 * (1.f / 32.f), d2 = v2 - s2 * (1.f / 32.f);
  float q1 = d1 * d1, q2 = d2 * d2;
  #pragma unroll
  for (int off = 16; off; off >>= 1) { q1 += __shfl_xor(q1, off); q2 += __shfl_xor(q2, off); }
  float o1 = d1 * rsqrtf(q1 * (1.f / 32.f) + 1e-5f) * g1w[c] + g1b[c];
  float o2 = d2 * rsqrtf(q2 * (1.f / 32.f) + 1e-5f) * g2w[c] + g2b[c];
  p[b * CH + c] = o1 + o2;
}

// ---------------- v[b][e] += sum_{c in chunk} p[b][c] * Wc[c][e] ----------------
__global__ __launch_bounds__(256) void colmm_kernel(const float* __restrict__ S,
                                                    const float* __restrict__ M,
                                                    float* __restrict__ O) {
  __shared__ float Sl[128][32];
  int t = threadIdx.x;
  int e0 = (blockIdx.x & 3) * 256, c0 = (blockIdx.x >> 2) * 128;
  for (int i = t; i < 4096; i += 256) {
    int c = i >> 5, b = i & 31;
    Sl[c][b] = S[b * CH + c0 + c];
  }
  __syncthreads();
  int e = e0 + t;
  float acc[32];
  #pragma unroll
  for (int b = 0; b < 32; ++b) acc[b] = 0.f;
  for (int c = 0; c < 128; ++c) {
    float wv = M[(size_t)(c0 + c) * CH + e];
    #pragma unroll
    for (int b = 0; b < 32; ++b) acc[b] += Sl[c][b] * wv;
  }
  #pragma unroll
  for (int b = 0; b < 32; ++b) atomicAdd(&O[b * CH + e], acc[b]);
}

// ---------------- logits s[b][l] = x[b][l][:] . v[b][:] ----------------
__global__ __launch_bounds__(256) void logits_kernel(const float* __restrict__ x,
                                                     const float* __restrict__ v,
                                                     float* __restrict__ s) {
  __shared__ float4 vl[256];
  int b = blockIdx.y, chunk = blockIdx.x, t = threadIdx.x;
  vl[t] = ((const float4*)(v + b * CH))[t];
  __syncthreads();
  int wv = t >> 6, lane = t & 63;
  for (int it = 0; it < 8; ++it) {
    int l = chunk * 32 + it * 4 + wv;
    const float4* xr = (const float4*)(x + ((size_t)b * L_SEQ + l) * CH);
    float acc = 0.f;
    #pragma unroll
    for (int rep = 0; rep < 4; ++rep) {
      float4 a = xr[rep * 64 + lane];
      float4 c = vl[rep * 64 + lane];
      acc += a.x * c.x + a.y * c.y + a.z * c.z + a.w * c.w;
    }
    #pragma unroll
    for (int off = 32; off; off >>= 1) acc += __shfl_xor(acc, off);
    if (lane == 0) s[b * L_SEQ + l] = acc;
  }
}

// ---------------- top-20 (desc, ties -> lower index), register-resident ------------
__global__ __launch_bounds__(256) void topk_kernel(const float* __restrict__ s,
                                                   int* __restrict__ idx_out) {
  int b = blockIdx.x, t = threadIdx.x;
  int lane = t & 63, w = t >> 6;
  __shared__ float lv[4];
  __shared__ int   li[4];
  float v[8];
  #pragma unroll
  for (int j = 0; j < 8; ++j) v[j] = s[b * L_SEQ + j * 256 + t];
  for (int k = 0; k < KSEL; ++k) {
    float bv = -INFINITY; int bi = 1 << 30;
    #pragma unroll
    for (int j = 0; j < 8; ++j) {
      int gi = j * 256 + t;
      if (v[j] > bv || (v[j] == bv && gi < bi)) { bv = v[j]; bi = gi; }
    }
    #pragma unroll
    for (int off = 32; off; off >>= 1) {
      float ov = __shfl_xor(bv, off); int oi = __shfl_xor(bi, off);
      if (ov > bv || (ov == bv && oi < bi)) { bv = ov; bi = oi; }
    }
    if (lane == 0) { lv[w] = bv; li[w] = bi; }
    __syncthreads();
    float fv = lv[0]; int fi = li[0];
    #pragma unroll
    for (int w2 = 1; w2 < 4; ++w2) {
      float ov = lv[w2]; int oi = li[w2];
      if (ov > fv || (ov == fv && oi < fi)) { fv = ov; fi = oi; }
    }
    if (t == 0) idx_out[b * KSEL + k] = fi;
    if ((fi & 255) == t) v[fi >> 8] = -INFINITY;
    __syncthreads();
  }
}

extern "C" void kernel_launch(void* const* d_in, const int* in_sizes, int n_in,
                              void* d_out, int out_size, void* d_ws, size_t ws_size,
                              hipStream_t stream) {
  const float* x   = (const float*)d_in[0];
  const float* W   = (const float*)d_in[1];
  const float* b   = (const float*)d_in[2];
  const float* W1  = (const float*)d_in[3];
  const float* b1  = (const float*)d_in[4];
  const float* Wm  = (const float*)d_in[5];
  const float* bm  = (const float*)d_in[6];
  const float* Wa  = (const float*)d_in[7];
  const float* ba  = (const float*)d_in[8];
  const float* g1w = (const float*)d_in[9];
  const float* g1b = (const float*)d_in[10];
  const float* g2w = (const float*)d_in[11];
  const float* g2b = (const float*)d_in[12];

  float* wsf = (float*)d_ws;
  float*    xsum = wsf + WS_XSUM;
  unsigned* ymax = (unsigned*)(wsf + WS_YMAX);
  float*    m1   = wsf + WS_M1;
  float*    amax = wsf + WS_AMAX;
  float*    t1   = wsf + WS_T1;
  float*    t2   = wsf + WS_T2;
  float*    p    = wsf + WS_P;
  float*    vvec = wsf + WS_V;
  float*    sbuf = wsf + WS_S;
  int*      tidx = (int*)(wsf + WS_TOPK);
  float*    bcv  = wsf + WS_BC;
  float*    Wc   = wsf + WS_WC;
  uint4*    wpak = (uint4*)(wsf + WS_WPAK);
  uint4*    wtpak = (uint4*)(wsf + WS_WTPAK);   // later reused as packed Wc

  packw_kernel<<<dim3(32, 8), 256, 0, stream>>>(W, wpak, wsf);     // + zero xsum/ymax/v
  packwt_kernel<<<dim3(32, 8), 256, 0, stream>>>(W, wtpak);
  mean_kernel<<<dim3(32, 32), 256, 0, stream>>>(x, xsum);
  gemm_max5<<<2048, 256, 0, stream>>>(x, wpak, ymax);

  wc_gemm<<<32, 256, 0, stream>>>(W1, wtpak, Wc);
  bc_kernel<<<128, 256, 0, stream>>>(W1, b, b1, bcv);
  packw_kernel<<<dim3(32, 8), 256, 0, stream>>>(Wc, wtpak, nullptr);  // wtpak := packed Wc

  poolmix_kernel<<<128, 256, 0, stream>>>(xsum, ymax, W, b, m1, amax);
  lin2_kernel<<<256, 256, 0, stream>>>(m1, amax, Wm, bm, Wa, ba, t1, t2);
  gnp_kernel<<<32, 1024, 0, stream>>>(t1, t2, g1w, g1b, g2w, g2b, p);
  colmm_kernel<<<32, 256, 0, stream>>>(p, Wc, vvec);                 // v = Wc^T p
  logits_kernel<<<dim3(64, 32), 256, 0, stream>>>(x, vvec, sbuf);
  topk_kernel<<<32, 256, 0, stream>>>(sbuf, tidx);
  out_gemm<<<20, 256, 0, stream>>>(x, tidx, wtpak, bcv, (float*)d_out);
}